// Round 1
// baseline (852.154 us; speedup 1.0000x reference)
//
#include <hip/hip_runtime.h>
#include <math.h>

#define NB 8
#define NP 19248
#define NC 81
#define NOBJ 8
#define NK 32
#define PHD 138
#define PWD 138
#define IH 550
#define IW 550

__device__ __forceinline__ float wave_sum(float v) {
  #pragma unroll
  for (int o = 32; o >= 1; o >>= 1) v += __shfl_xor(v, o);
  return v;
}
__device__ __forceinline__ int wave_sum_i(int v) {
  #pragma unroll
  for (int o = 32; o >= 1; o >>= 1) v += __shfl_xor(v, o);
  return v;
}

// accum layout: [0]=loss_b_raw, [1]=loss_c, [2]=loss_m_raw
__global__ void init_kernel(float* accum) {
  if (threadIdx.x < 4) accum[threadIdx.x] = 0.f;
}

// One block per batch: IoU matching, forced best-prior matches, conf/pmi, inline box loss.
__global__ __launch_bounds__(256) void match_kernel(
    const float* __restrict__ priors, const float* __restrict__ box_gt,
    const int* __restrict__ class_gt, const float* __restrict__ box_p,
    float* __restrict__ prior_max, int* __restrict__ prior_arg,
    int* __restrict__ conf, int* __restrict__ pmi, float* accum)
{
  int b = blockIdx.x, tid = threadIdx.x;
  int lane = tid & 63, wid = tid >> 6;
  __shared__ float gx1[NOBJ], gy1[NOBJ], gx2[NOBJ], gy2[NOBJ], garea[NOBJ];
  __shared__ float red_v[NOBJ][4];
  __shared__ int   red_i[NOBJ][4];
  __shared__ float lbw[4];

  if (tid < NOBJ) {
    const float* g = box_gt + (b * NOBJ + tid) * 4;
    float x1 = g[0], y1 = g[1], x2 = g[2], y2 = g[3];
    gx1[tid] = x1; gy1[tid] = y1; gx2[tid] = x2; gy2[tid] = y2;
    garea[tid] = (x2 - x1) * (y2 - y1);
  }
  __syncthreads();

  float bestv[NOBJ]; int besti[NOBJ];
  #pragma unroll
  for (int j = 0; j < NOBJ; j++) { bestv[j] = -1.0f; besti[j] = 0x7fffffff; }

  for (int p = tid; p < NP; p += 256) {
    const float* pr = priors + p * 4;
    float cx = pr[0], cy = pr[1], w = pr[2], h = pr[3];
    float dx1 = cx - w * 0.5f, dy1 = cy - h * 0.5f;
    float dx2 = cx + w * 0.5f, dy2 = cy + h * 0.5f;
    float darea = (dx2 - dx1) * (dy2 - dy1);
    float pmax = -1.f; int parg = 0;
    #pragma unroll
    for (int j = 0; j < NOBJ; j++) {
      float ix = fmaxf(fminf(gx2[j], dx2) - fmaxf(gx1[j], dx1), 0.f);
      float iy = fmaxf(fminf(gy2[j], dy2) - fmaxf(gy1[j], dy1), 0.f);
      float inter = ix * iy;
      float iou = inter / (garea[j] + darea - inter);
      if (j == 0) { pmax = iou; parg = 0; }
      else if (iou > pmax) { pmax = iou; parg = j; }   // strict > : first-index tie-break
      if (iou > bestv[j] || (iou == bestv[j] && p < besti[j])) { bestv[j] = iou; besti[j] = p; }
    }
    prior_max[b * NP + p] = pmax;
    prior_arg[b * NP + p] = parg;
  }

  // block argmax per gt box (tie-break: smaller prior index)
  #pragma unroll
  for (int j = 0; j < NOBJ; j++) {
    float v = bestv[j]; int i = besti[j];
    #pragma unroll
    for (int o = 32; o >= 1; o >>= 1) {
      float ov = __shfl_down(v, o); int oi = __shfl_down(i, o);
      if (ov > v || (ov == v && oi < i)) { v = ov; i = oi; }
    }
    if (lane == 0) { red_v[j][wid] = v; red_i[j][wid] = i; }
  }
  __syncthreads();
  if (tid == 0) {
    // forced matches, sequential j so later j wins on (unlikely) duplicates
    for (int j = 0; j < NOBJ; j++) {
      float v = red_v[j][0]; int i = red_i[j][0];
      for (int w2 = 1; w2 < 4; w2++) {
        if (red_v[j][w2] > v || (red_v[j][w2] == v && red_i[j][w2] < i)) { v = red_v[j][w2]; i = red_i[j][w2]; }
      }
      prior_max[b * NP + i] = 2.0f;
      prior_arg[b * NP + i] = j;
    }
  }
  __syncthreads();

  // pass 2: conf, pmi, inline smooth-L1 box loss (positives only)
  float lb = 0.f;
  for (int p = tid; p < NP; p += 256) {
    float m = prior_max[b * NP + p];
    int j = prior_arg[b * NP + p];
    int cf = class_gt[b * NOBJ + j] + 1;
    if (m < 0.5f) cf = -1;
    if (m < 0.4f) cf = 0;
    conf[b * NP + p] = cf;
    pmi[b * NP + p] = j;
    if (cf > 0) {
      const float* pr = priors + p * 4;
      float pcx = pr[0], pcy = pr[1], prw = pr[2], prh = pr[3];
      float ox = ((gx1[j] + gx2[j]) * 0.5f - pcx) / (0.1f * prw);
      float oy = ((gy1[j] + gy2[j]) * 0.5f - pcy) / (0.1f * prh);
      float ow = logf((gx2[j] - gx1[j]) / prw) / 0.2f;
      float oh = logf((gy2[j] - gy1[j]) / prh) / 0.2f;
      const float* bp = box_p + (b * NP + p) * 4;
      float o4[4] = {ox, oy, ow, oh};
      #pragma unroll
      for (int c = 0; c < 4; c++) {
        float d = fabsf(bp[c] - o4[c]);
        lb += (d < 1.f) ? 0.5f * d * d : d - 0.5f;
      }
    }
  }
  lb = wave_sum(lb);
  if (lane == 0) lbw[wid] = lb;
  __syncthreads();
  if (tid == 0) atomicAdd(&accum[0], lbw[0] + lbw[1] + lbw[2] + lbw[3]);
}

// Ordered compaction of positive priors (first 128 by index), num_pos/num_neg/scale per batch.
__global__ __launch_bounds__(256) void poslist_kernel(
    const int* __restrict__ conf, int* __restrict__ pos_list,
    int* __restrict__ npos_arr, int* __restrict__ nneg_arr, float* __restrict__ scale_arr)
{
  int b = blockIdx.x, tid = threadIdx.x;
  int lane = tid & 63, wid = tid >> 6;
  __shared__ int wcnt[4];
  __shared__ int base;
  if (tid == 0) base = 0;
  __syncthreads();
  for (int start = 0; start < NP; start += 256) {
    int p = start + tid;
    bool flag = (p < NP) && (conf[b * NP + p] > 0);
    unsigned long long m = __ballot(flag);
    if (lane == 0) wcnt[wid] = __popcll(m);
    __syncthreads();
    int pre = base;
    for (int w = 0; w < wid; w++) pre += wcnt[w];
    int tot = wcnt[0] + wcnt[1] + wcnt[2] + wcnt[3];
    int rank = pre + __popcll(m & ((1ull << lane) - 1ull));
    if (flag && rank < 128) pos_list[b * 128 + rank] = p;
    __syncthreads();
    if (tid == 0) base += tot;
    __syncthreads();
  }
  if (tid == 0) {
    int np = base;
    npos_arr[b] = np;
    int nn = 3 * np; if (nn > NP - 1) nn = NP - 1;
    nneg_arr[b] = nn;
    scale_arr[b] = (np > 100) ? (float)np / 100.0f : 1.0f;
  }
}

// One wave per (b,p) row: logsumexp over 81 classes -> mark (== negative nll), positive nll.
__global__ __launch_bounds__(256) void mark_kernel(
    const float* __restrict__ class_p, const int* __restrict__ conf,
    float* __restrict__ marks, float* accum)
{
  int wid = threadIdx.x >> 6, lane = threadIdx.x & 63;
  int row = blockIdx.x * 4 + wid;
  if (row >= NB * NP) return;
  const float* cp = class_p + (size_t)row * NC;
  float v0 = cp[lane];
  bool has1 = (lane + 64) < NC;
  float v1 = has1 ? cp[lane + 64] : -INFINITY;
  float m = fmaxf(v0, v1);
  #pragma unroll
  for (int o = 32; o >= 1; o >>= 1) m = fmaxf(m, __shfl_xor(m, o));
  float s = expf(v0 - m) + (has1 ? expf(v1 - m) : 0.f);
  s = wave_sum(s);
  float lse = m + logf(s);
  int cf = conf[row];
  float cp0 = __shfl(v0, 0);
  if (lane == 0) marks[row] = (cf != 0) ? 0.f : (lse - cp0);
  if (cf > 0) {
    float vt = (cf < 64) ? __shfl(v0, cf) : __shfl(v1, cf - 64);
    if (lane == 0) atomicAdd(&accum[1], lse - vt);
  }
}

// Per batch: k-th largest mark via binary search on uint bits; sum of top-k marks -> loss_c.
__global__ __launch_bounds__(256) void select_kernel(
    const float* __restrict__ marks, const int* __restrict__ nneg_arr, float* accum)
{
  int b = blockIdx.x, tid = threadIdx.x;
  int lane = tid & 63, wid = tid >> 6;
  const float* mk = marks + b * NP;
  int k = nneg_arr[b];
  __shared__ unsigned slo, shi;
  __shared__ int wred[4];
  __shared__ float fred[4];
  if (tid == 0) { slo = 0u; shi = 0x7f800000u; }
  __syncthreads();
  while (true) {
    unsigned lo = slo, hi = shi;
    if (hi - lo <= 1u) break;
    unsigned mid = lo + ((hi - lo) >> 1);
    float fmid = __uint_as_float(mid);
    int cnt = 0;
    for (int p = tid; p < NP; p += 256) cnt += (mk[p] >= fmid) ? 1 : 0;
    cnt = wave_sum_i(cnt);
    if (lane == 0) wred[wid] = cnt;
    __syncthreads();
    if (tid == 0) {
      int tot = wred[0] + wred[1] + wred[2] + wred[3];
      if (tot >= k) slo = mid; else shi = mid;
    }
    __syncthreads();
  }
  float thr = __uint_as_float(slo);
  float s = 0.f;
  for (int p = tid; p < NP; p += 256) { float v = mk[p]; if (v >= thr) s += v; }
  s = wave_sum(s);
  if (lane == 0) fred[wid] = s;
  __syncthreads();
  if (tid == 0) atomicAdd(&accum[1], fred[0] + fred[1] + fred[2] + fred[3]);
}

// Antialiased linear resize (550->138, triangle kernel, per-dim normalized) + >0.5 threshold.
__global__ __launch_bounds__(256) void resize_kernel(
    const float* __restrict__ mask_gt, unsigned char* __restrict__ dm)
{
  int idx = blockIdx.x * 256 + threadIdx.x;
  const int TOT = NB * NOBJ * PHD * PWD;
  if (idx >= TOT) return;
  int ox = idx % PWD;
  int oy = (idx / PWD) % PHD;
  int bn = idx / (PWD * PHD);
  const float ks = (float)IH / (float)PHD;  // 550/138, same both dims
  float sy = (oy + 0.5f) * ks - 0.5f;
  float sx = (ox + 0.5f) * ks - 0.5f;
  int ylo = (int)ceilf(sy - ks); if (ylo < 0) ylo = 0;
  int yhi = (int)floorf(sy + ks); if (yhi > IH - 1) yhi = IH - 1;
  int xlo = (int)ceilf(sx - ks); if (xlo < 0) xlo = 0;
  int xhi = (int)floorf(sx + ks); if (xhi > IW - 1) xhi = IW - 1;
  float wsy = 0.f, wsx = 0.f;
  for (int j = ylo; j <= yhi; j++) wsy += fmaxf(0.f, 1.f - fabsf(sy - (float)j) / ks);
  for (int j = xlo; j <= xhi; j++) wsx += fmaxf(0.f, 1.f - fabsf(sx - (float)j) / ks);
  const float* mg = mask_gt + (size_t)bn * IH * IW;
  float acc = 0.f;
  for (int jy = ylo; jy <= yhi; jy++) {
    float wy = fmaxf(0.f, 1.f - fabsf(sy - (float)jy) / ks);
    const float* rowp = mg + (size_t)jy * IW;
    float accx = 0.f;
    for (int jx = xlo; jx <= xhi; jx++) {
      float wx = fmaxf(0.f, 1.f - fabsf(sx - (float)jx) / ks);
      accx += wx * rowp[jx];
    }
    acc += wy * accx;
  }
  float val = acc / (wsy * wsx);
  dm[idx] = (val > 0.5f) ? 1 : 0;
}

// Pixel-major mask loss: per pixel read proto once + 8 dm bits; loop <=100 masks from LDS.
__global__ __launch_bounds__(256) void maskloss_kernel(
    const float* __restrict__ proto_p, const float* __restrict__ coef_p,
    const float* __restrict__ box_gt, const int* __restrict__ pmi,
    const unsigned char* __restrict__ dm, const int* __restrict__ pos_list,
    const int* __restrict__ npos_arr, const float* __restrict__ scale_arr,
    float* accum)
{
  int b = blockIdx.y, tid = threadIdx.x;
  __shared__ float s_pc[100 * NK];
  __shared__ float s_x1[100], s_x2[100], s_y1[100], s_y2[100], s_inv[100];
  __shared__ int s_gi[100];
  __shared__ float fr[4];
  int np = npos_arr[b];
  int mb = np < 100 ? np : 100;
  for (int i = tid; i < mb * NK; i += 256) {
    int kk = i / NK, c = i % NK;
    int p = pos_list[b * 128 + kk];
    s_pc[i] = coef_p[((size_t)(b * NP) + p) * NK + c];
  }
  for (int kk = tid; kk < mb; kk += 256) {
    int p = pos_list[b * 128 + kk];
    int gi = pmi[b * NP + p];
    const float* g = box_gt + (b * NOBJ + gi) * 4;
    float bx1 = g[0], by1 = g[1], bx2 = g[2], by2 = g[3];
    float ax = bx1 * 138.f, bx = bx2 * 138.f;
    float x1 = fminf(ax, bx), x2 = fmaxf(ax, bx);
    x1 = fmaxf(x1 - 1.f, 0.f);
    x2 = fminf(x2 + 1.f, 138.f);
    float ay = by1 * 138.f, by2f = by2 * 138.f;
    float y1 = fminf(ay, by2f), y2 = fmaxf(ay, by2f);
    y1 = fmaxf(y1 - 1.f, 0.f);
    y2 = fminf(y2 + 1.f, 138.f);
    s_x1[kk] = x1; s_x2[kk] = x2; s_y1[kk] = y1; s_y2[kk] = y2;
    float wk = bx2 - bx1, hk = by2 - by1;
    s_inv[kk] = 1.f / (wk * hk);
    s_gi[kk] = gi;
  }
  __syncthreads();
  int px = blockIdx.x * 256 + tid;
  float acc = 0.f;
  if (px < PHD * PWD && mb > 0) {
    int y = px / PWD, x = px % PWD;
    float fx = (float)x, fy = (float)y;
    float a[NK];
    const float* pp = proto_p + ((size_t)(b * PHD * PWD) + px) * NK;
    #pragma unroll
    for (int c = 0; c < NK; c++) a[c] = pp[c];
    int gtbits = 0;
    #pragma unroll
    for (int n = 0; n < NOBJ; n++)
      gtbits |= ((int)dm[(size_t)(b * NOBJ + n) * (PHD * PWD) + px]) << n;
    const float PLO = 1e-7f;
    const float PHIv = (float)(1.0 - 1e-7);
    for (int kk = 0; kk < mb; kk++) {
      float logit = 0.f;
      #pragma unroll
      for (int c = 0; c < NK; c++) logit += a[c] * s_pc[kk * NK + c];
      bool inb = (fx >= s_x1[kk]) && (fx < s_x2[kk]) && (fy >= s_y1[kk]) && (fy < s_y2[kk]);
      float p_ = inb ? (1.f / (1.f + expf(-logit))) : 0.f;
      p_ = fminf(fmaxf(p_, PLO), PHIv);
      float gt = (float)((gtbits >> s_gi[kk]) & 1);
      float bce = -(gt * logf(p_) + (1.f - gt) * log1pf(-p_));
      acc += bce * s_inv[kk];
    }
  }
  acc = wave_sum(acc);
  int lane = tid & 63, wid = tid >> 6;
  if (lane == 0) fr[wid] = acc;
  __syncthreads();
  if (tid == 0) atomicAdd(&accum[2], (fr[0] + fr[1] + fr[2] + fr[3]) * scale_arr[b]);
}

__global__ void finalize_kernel(const float* accum, float* out) {
  out[0] = 1.5f * accum[0] + accum[1] + accum[2] * (6.125f / (138.f * 138.f));
}

extern "C" void kernel_launch(void* const* d_in, const int* in_sizes, int n_in,
                              void* d_out, int out_size, void* d_ws, size_t ws_size,
                              hipStream_t stream) {
  const float* class_p  = (const float*)d_in[0];
  const float* box_p    = (const float*)d_in[1];
  const float* coef_p   = (const float*)d_in[2];
  const float* proto_p  = (const float*)d_in[3];
  const float* priors   = (const float*)d_in[4];
  const float* box_gt   = (const float*)d_in[5];
  const float* mask_gt  = (const float*)d_in[6];
  const int*   class_gt = (const int*)d_in[7];

  char* ws = (char*)d_ws;
  const size_t BP = (size_t)NB * NP;            // 153984
  float* prior_max = (float*)(ws + 0);          // BP f32
  int*   prior_arg = (int*)(ws + 615936);       // BP i32
  int*   conf      = (int*)(ws + 1231872);      // BP i32
  int*   pmi       = (int*)(ws + 1847808);      // BP i32
  float* marks     = (float*)(ws + 2463744);    // BP f32
  unsigned char* dm = (unsigned char*)(ws + 3079680); // NB*NOBJ*138*138 u8 = 1218816
  int*   pos_list  = (int*)(ws + 4298496);      // NB*128 i32
  int*   npos_arr  = (int*)(ws + 4302592);      // NB i32
  int*   nneg_arr  = (int*)(ws + 4302624);      // NB i32
  float* scale_arr = (float*)(ws + 4302656);    // NB f32
  float* accum     = (float*)(ws + 4302688);    // 4 f32
  (void)BP; (void)in_sizes; (void)n_in; (void)out_size; (void)ws_size;

  init_kernel<<<1, 64, 0, stream>>>(accum);
  match_kernel<<<NB, 256, 0, stream>>>(priors, box_gt, class_gt, box_p,
                                       prior_max, prior_arg, conf, pmi, accum);
  poslist_kernel<<<NB, 256, 0, stream>>>(conf, pos_list, npos_arr, nneg_arr, scale_arr);
  mark_kernel<<<(NB * NP + 3) / 4, 256, 0, stream>>>(class_p, conf, marks, accum);
  select_kernel<<<NB, 256, 0, stream>>>(marks, nneg_arr, accum);
  resize_kernel<<<(NB * NOBJ * PHD * PWD + 255) / 256, 256, 0, stream>>>(mask_gt, dm);
  dim3 g((PHD * PWD + 255) / 256, NB);
  maskloss_kernel<<<g, 256, 0, stream>>>(proto_p, coef_p, box_gt, pmi, dm,
                                         pos_list, npos_arr, scale_arr, accum);
  finalize_kernel<<<1, 1, 0, stream>>>(accum, (float*)d_out);
}

// Round 2
// 534.561 us; speedup vs baseline: 1.5941x; 1.5941x over previous
//
#include <hip/hip_runtime.h>
#include <math.h>

#define NB 8
#define NP 19248
#define NC 81
#define NOBJ 8
#define NK 32
#define PHD 138
#define PWD 138
#define IH 550
#define IW 550

__device__ __forceinline__ float wave_sum(float v) {
  #pragma unroll
  for (int o = 32; o >= 1; o >>= 1) v += __shfl_xor(v, o);
  return v;
}
__device__ __forceinline__ int wave_sum_i(int v) {
  #pragma unroll
  for (int o = 32; o >= 1; o >>= 1) v += __shfl_xor(v, o);
  return v;
}

// accum layout: [0]=loss_b_raw, [1]=loss_c, [2]=loss_m_raw
__global__ void init_kernel(float* accum, unsigned long long* forced) {
  if (threadIdx.x < 4) accum[threadIdx.x] = 0.f;
  if (threadIdx.x < NB * NOBJ) forced[threadIdx.x] = 0ull;
}

// grid (76, NB): one prior per thread. Per-prior max/arg + per-gt argmax via packed u64 atomicMax.
__global__ __launch_bounds__(256) void match1_kernel(
    const float* __restrict__ priors, const float* __restrict__ box_gt,
    float* __restrict__ prior_max, int* __restrict__ prior_arg,
    unsigned long long* __restrict__ forced)
{
  int b = blockIdx.y, tid = threadIdx.x;
  int p = blockIdx.x * 256 + tid;
  int lane = tid & 63;
  __shared__ float gx1[NOBJ], gy1[NOBJ], gx2[NOBJ], gy2[NOBJ], garea[NOBJ];
  if (tid < NOBJ) {
    const float* g = box_gt + (b * NOBJ + tid) * 4;
    float x1 = g[0], y1 = g[1], x2 = g[2], y2 = g[3];
    gx1[tid] = x1; gy1[tid] = y1; gx2[tid] = x2; gy2[tid] = y2;
    garea[tid] = (x2 - x1) * (y2 - y1);
  }
  __syncthreads();

  bool act = p < NP;
  float dx1 = 0, dy1 = 0, dx2 = 0, dy2 = 0, darea = 1.f;
  if (act) {
    const float* pr = priors + p * 4;
    float cx = pr[0], cy = pr[1], w = pr[2], h = pr[3];
    dx1 = cx - w * 0.5f; dy1 = cy - h * 0.5f;
    dx2 = cx + w * 0.5f; dy2 = cy + h * 0.5f;
    darea = (dx2 - dx1) * (dy2 - dy1);
  }
  float pmax = -1.f; int parg = 0;
  unsigned long long pk[NOBJ];
  #pragma unroll
  for (int j = 0; j < NOBJ; j++) {
    float ix = fmaxf(fminf(gx2[j], dx2) - fmaxf(gx1[j], dx1), 0.f);
    float iy = fmaxf(fminf(gy2[j], dy2) - fmaxf(gy1[j], dy1), 0.f);
    float inter = ix * iy;
    float iou = inter / (garea[j] + darea - inter);
    if (j == 0) { pmax = iou; parg = 0; }
    else if (iou > pmax) { pmax = iou; parg = j; }   // strict > : first-index tie-break
    // pack: iou (>=0) in high 32, complemented index in low 32 (equal iou -> smaller p wins)
    pk[j] = act ? ((((unsigned long long)__float_as_uint(iou)) << 32)
                   | (unsigned long long)(0x7fffffffu - (unsigned)p))
                : 0ull;
  }
  if (act) {
    prior_max[b * NP + p] = pmax;
    prior_arg[b * NP + p] = parg;
  }
  #pragma unroll
  for (int j = 0; j < NOBJ; j++) {
    unsigned long long v = pk[j];
    #pragma unroll
    for (int o = 32; o >= 1; o >>= 1) {
      unsigned long long ov = __shfl_xor(v, o);
      if (ov > v) v = ov;
    }
    if (lane == 0) atomicMax(&forced[b * NOBJ + j], v);
  }
}

// Apply forced matches sequentially per batch (later j wins on duplicates).
__global__ void match2_kernel(const unsigned long long* __restrict__ forced,
                              float* __restrict__ prior_max, int* __restrict__ prior_arg) {
  int b = threadIdx.x;
  if (b < NB) {
    for (int j = 0; j < NOBJ; j++) {
      unsigned long long v = forced[b * NOBJ + j];
      int i = 0x7fffffff - (int)(v & 0xffffffffull);
      prior_max[b * NP + i] = 2.0f;
      prior_arg[b * NP + i] = j;
    }
  }
}

// grid (76, NB): conf per prior + inline smooth-L1 box loss for positives.
__global__ __launch_bounds__(256) void conf_kernel(
    const float* __restrict__ priors, const float* __restrict__ box_gt,
    const int* __restrict__ class_gt, const float* __restrict__ box_p,
    const float* __restrict__ prior_max, const int* __restrict__ prior_arg,
    int* __restrict__ conf, float* accum)
{
  int b = blockIdx.y, tid = threadIdx.x;
  int p = blockIdx.x * 256 + tid;
  int lane = tid & 63, wid = tid >> 6;
  __shared__ float lbw[4];
  float lb = 0.f;
  if (p < NP) {
    float m = prior_max[b * NP + p];
    int j = prior_arg[b * NP + p];
    int cf = class_gt[b * NOBJ + j] + 1;
    if (m < 0.5f) cf = -1;
    if (m < 0.4f) cf = 0;
    conf[b * NP + p] = cf;
    if (cf > 0) {
      const float* g = box_gt + (b * NOBJ + j) * 4;
      float x1 = g[0], y1 = g[1], x2 = g[2], y2 = g[3];
      const float* pr = priors + p * 4;
      float pcx = pr[0], pcy = pr[1], prw = pr[2], prh = pr[3];
      float o4[4];
      o4[0] = ((x1 + x2) * 0.5f - pcx) / (0.1f * prw);
      o4[1] = ((y1 + y2) * 0.5f - pcy) / (0.1f * prh);
      o4[2] = logf((x2 - x1) / prw) / 0.2f;
      o4[3] = logf((y2 - y1) / prh) / 0.2f;
      const float* bp = box_p + (b * NP + p) * 4;
      #pragma unroll
      for (int c = 0; c < 4; c++) {
        float d = fabsf(bp[c] - o4[c]);
        lb += (d < 1.f) ? 0.5f * d * d : d - 0.5f;
      }
    }
  }
  lb = wave_sum(lb);
  if (lane == 0) lbw[wid] = lb;
  __syncthreads();
  if (tid == 0) atomicAdd(&accum[0], lbw[0] + lbw[1] + lbw[2] + lbw[3]);
}

// One block per batch: segment count -> LDS scan -> ordered scatter of first 128 positives.
__global__ __launch_bounds__(256) void poslist_kernel(
    const int* __restrict__ conf, int* __restrict__ pos_list,
    int* __restrict__ npos_arr, int* __restrict__ nneg_arr, float* __restrict__ scale_arr)
{
  int b = blockIdx.x, tid = threadIdx.x;
  const int SEG = 76;  // 256*76 = 19456 >= NP
  int s0 = tid * SEG, s1 = s0 + SEG; if (s1 > NP) s1 = NP;
  int cnt = 0;
  for (int p = s0; p < s1; p++) cnt += (conf[b * NP + p] > 0) ? 1 : 0;
  __shared__ int sc[256];
  sc[tid] = cnt;
  __syncthreads();
  #pragma unroll
  for (int off = 1; off < 256; off <<= 1) {
    int v = (tid >= off) ? sc[tid - off] : 0;
    __syncthreads();
    sc[tid] += v;
    __syncthreads();
  }
  int base = sc[tid] - cnt;   // exclusive prefix
  if (cnt > 0 && base < 128) {
    int r = base;
    for (int p = s0; p < s1; p++) {
      if (conf[b * NP + p] > 0) {
        if (r < 128) pos_list[b * 128 + r] = p;
        r++;
      }
    }
  }
  if (tid == 255) {
    int np = sc[255];
    npos_arr[b] = np;
    int nn = 3 * np; if (nn > NP - 1) nn = NP - 1;
    nneg_arr[b] = nn;
    scale_arr[b] = (np > 100) ? (float)np / 100.0f : 1.0f;
  }
}

// One wave per (b,p) row: logsumexp over 81 classes -> mark (== negative nll), positive nll.
__global__ __launch_bounds__(256) void mark_kernel(
    const float* __restrict__ class_p, const int* __restrict__ conf,
    float* __restrict__ marks, float* accum)
{
  int wid = threadIdx.x >> 6, lane = threadIdx.x & 63;
  int row = blockIdx.x * 4 + wid;
  if (row >= NB * NP) return;
  const float* cp = class_p + (size_t)row * NC;
  float v0 = cp[lane];
  bool has1 = (lane + 64) < NC;
  float v1 = has1 ? cp[lane + 64] : -INFINITY;
  float m = fmaxf(v0, v1);
  #pragma unroll
  for (int o = 32; o >= 1; o >>= 1) m = fmaxf(m, __shfl_xor(m, o));
  float s = expf(v0 - m) + (has1 ? expf(v1 - m) : 0.f);
  s = wave_sum(s);
  float lse = m + logf(s);
  int cf = conf[row];
  float cp0 = __shfl(v0, 0);
  if (lane == 0) marks[row] = (cf != 0) ? 0.f : (lse - cp0);
  if (cf > 0) {
    float vt = (cf < 64) ? __shfl(v0, cf) : __shfl(v1, cf - 64);
    if (lane == 0) atomicAdd(&accum[1], lse - vt);
  }
}

// Per batch, 1024 threads: marks cached in 19 regs/thread; 31-step binary search on uint bits.
__global__ __launch_bounds__(1024) void select_kernel(
    const float* __restrict__ marks, const int* __restrict__ nneg_arr, float* accum)
{
  int b = blockIdx.x, tid = threadIdx.x;
  int lane = tid & 63, wid = tid >> 6;
  float v[19];
  #pragma unroll
  for (int i = 0; i < 19; i++) {
    int p = i * 1024 + tid;
    v[i] = (p < NP) ? marks[b * NP + p] : 0.f;  // pad 0: midpoints are >0, pads never counted
  }
  int k = nneg_arr[b];
  __shared__ unsigned slo, shi;
  __shared__ int wred[16];
  __shared__ float fred[16];
  if (tid == 0) { slo = 0u; shi = 0x7f800000u; }
  __syncthreads();
  while (true) {
    unsigned lo = slo, hi = shi;
    if (hi - lo <= 1u) break;
    unsigned mid = lo + ((hi - lo) >> 1);
    float fmid = __uint_as_float(mid);
    int cnt = 0;
    #pragma unroll
    for (int i = 0; i < 19; i++) cnt += (v[i] >= fmid) ? 1 : 0;
    cnt = wave_sum_i(cnt);
    if (lane == 0) wred[wid] = cnt;
    __syncthreads();
    if (tid == 0) {
      int tot = 0;
      #pragma unroll
      for (int w = 0; w < 16; w++) tot += wred[w];
      if (tot >= k) slo = mid; else shi = mid;
    }
    __syncthreads();
  }
  float thr = __uint_as_float(slo);
  float s = 0.f;
  #pragma unroll
  for (int i = 0; i < 19; i++) if (v[i] >= thr) s += v[i];
  s = wave_sum(s);
  if (lane == 0) fred[wid] = s;
  __syncthreads();
  if (tid == 0) {
    float t = 0.f;
    #pragma unroll
    for (int w = 0; w < 16; w++) t += fred[w];
    atomicAdd(&accum[1], t);
  }
}

// Antialiased linear resize (550->138, triangle kernel, per-dim normalized) + >0.5 threshold.
__global__ __launch_bounds__(256) void resize_kernel(
    const float* __restrict__ mask_gt, unsigned char* __restrict__ dm)
{
  int idx = blockIdx.x * 256 + threadIdx.x;
  const int TOT = NB * NOBJ * PHD * PWD;
  if (idx >= TOT) return;
  int ox = idx % PWD;
  int oy = (idx / PWD) % PHD;
  int bn = idx / (PWD * PHD);
  const float ks = (float)IH / (float)PHD;  // 550/138, same both dims
  float sy = (oy + 0.5f) * ks - 0.5f;
  float sx = (ox + 0.5f) * ks - 0.5f;
  int ylo = (int)ceilf(sy - ks); if (ylo < 0) ylo = 0;
  int yhi = (int)floorf(sy + ks); if (yhi > IH - 1) yhi = IH - 1;
  int xlo = (int)ceilf(sx - ks); if (xlo < 0) xlo = 0;
  int xhi = (int)floorf(sx + ks); if (xhi > IW - 1) xhi = IW - 1;
  float wsy = 0.f, wsx = 0.f;
  for (int j = ylo; j <= yhi; j++) wsy += fmaxf(0.f, 1.f - fabsf(sy - (float)j) / ks);
  for (int j = xlo; j <= xhi; j++) wsx += fmaxf(0.f, 1.f - fabsf(sx - (float)j) / ks);
  const float* mg = mask_gt + (size_t)bn * IH * IW;
  float acc = 0.f;
  for (int jy = ylo; jy <= yhi; jy++) {
    float wy = fmaxf(0.f, 1.f - fabsf(sy - (float)jy) / ks);
    const float* rowp = mg + (size_t)jy * IW;
    float accx = 0.f;
    for (int jx = xlo; jx <= xhi; jx++) {
      float wx = fmaxf(0.f, 1.f - fabsf(sx - (float)jx) / ks);
      accx += wx * rowp[jx];
    }
    acc += wy * accx;
  }
  float val = acc / (wsy * wsx);
  dm[idx] = (val > 0.5f) ? 1 : 0;
}

// Pixel-major mask loss: per pixel read proto once + 8 dm bits; loop <=100 masks from LDS.
__global__ __launch_bounds__(256) void maskloss_kernel(
    const float* __restrict__ proto_p, const float* __restrict__ coef_p,
    const float* __restrict__ box_gt, const int* __restrict__ pmi,
    const unsigned char* __restrict__ dm, const int* __restrict__ pos_list,
    const int* __restrict__ npos_arr, const float* __restrict__ scale_arr,
    float* accum)
{
  int b = blockIdx.y, tid = threadIdx.x;
  __shared__ float s_pc[100 * NK];
  __shared__ float s_x1[100], s_x2[100], s_y1[100], s_y2[100], s_inv[100];
  __shared__ int s_gi[100];
  __shared__ float fr[4];
  int np = npos_arr[b];
  int mb = np < 100 ? np : 100;
  for (int i = tid; i < mb * NK; i += 256) {
    int kk = i / NK, c = i % NK;
    int p = pos_list[b * 128 + kk];
    s_pc[i] = coef_p[((size_t)(b * NP) + p) * NK + c];
  }
  for (int kk = tid; kk < mb; kk += 256) {
    int p = pos_list[b * 128 + kk];
    int gi = pmi[b * NP + p];
    const float* g = box_gt + (b * NOBJ + gi) * 4;
    float bx1 = g[0], by1 = g[1], bx2 = g[2], by2 = g[3];
    float ax = bx1 * 138.f, bx = bx2 * 138.f;
    float x1 = fminf(ax, bx), x2 = fmaxf(ax, bx);
    x1 = fmaxf(x1 - 1.f, 0.f);
    x2 = fminf(x2 + 1.f, 138.f);
    float ay = by1 * 138.f, by2f = by2 * 138.f;
    float y1 = fminf(ay, by2f), y2 = fmaxf(ay, by2f);
    y1 = fmaxf(y1 - 1.f, 0.f);
    y2 = fminf(y2 + 1.f, 138.f);
    s_x1[kk] = x1; s_x2[kk] = x2; s_y1[kk] = y1; s_y2[kk] = y2;
    float wk = bx2 - bx1, hk = by2 - by1;
    s_inv[kk] = 1.f / (wk * hk);
    s_gi[kk] = gi;
  }
  __syncthreads();
  int px = blockIdx.x * 256 + tid;
  float acc = 0.f;
  if (px < PHD * PWD && mb > 0) {
    int y = px / PWD, x = px % PWD;
    float fx = (float)x, fy = (float)y;
    float a[NK];
    const float* pp = proto_p + ((size_t)(b * PHD * PWD) + px) * NK;
    #pragma unroll
    for (int c = 0; c < NK; c++) a[c] = pp[c];
    int gtbits = 0;
    #pragma unroll
    for (int n = 0; n < NOBJ; n++)
      gtbits |= ((int)dm[(size_t)(b * NOBJ + n) * (PHD * PWD) + px]) << n;
    const float PLO = 1e-7f;
    const float PHIv = (float)(1.0 - 1e-7);
    for (int kk = 0; kk < mb; kk++) {
      float logit = 0.f;
      #pragma unroll
      for (int c = 0; c < NK; c++) logit += a[c] * s_pc[kk * NK + c];
      bool inb = (fx >= s_x1[kk]) && (fx < s_x2[kk]) && (fy >= s_y1[kk]) && (fy < s_y2[kk]);
      float p_ = inb ? (1.f / (1.f + expf(-logit))) : 0.f;
      p_ = fminf(fmaxf(p_, PLO), PHIv);
      float gt = (float)((gtbits >> s_gi[kk]) & 1);
      float bce = -(gt * logf(p_) + (1.f - gt) * log1pf(-p_));
      acc += bce * s_inv[kk];
    }
  }
  acc = wave_sum(acc);
  int lane = tid & 63, wid = tid >> 6;
  if (lane == 0) fr[wid] = acc;
  __syncthreads();
  if (tid == 0) atomicAdd(&accum[2], (fr[0] + fr[1] + fr[2] + fr[3]) * scale_arr[b]);
}

__global__ void finalize_kernel(const float* accum, float* out) {
  out[0] = 1.5f * accum[0] + accum[1] + accum[2] * (6.125f / (138.f * 138.f));
}

extern "C" void kernel_launch(void* const* d_in, const int* in_sizes, int n_in,
                              void* d_out, int out_size, void* d_ws, size_t ws_size,
                              hipStream_t stream) {
  const float* class_p  = (const float*)d_in[0];
  const float* box_p    = (const float*)d_in[1];
  const float* coef_p   = (const float*)d_in[2];
  const float* proto_p  = (const float*)d_in[3];
  const float* priors   = (const float*)d_in[4];
  const float* box_gt   = (const float*)d_in[5];
  const float* mask_gt  = (const float*)d_in[6];
  const int*   class_gt = (const int*)d_in[7];

  char* ws = (char*)d_ws;
  float* prior_max = (float*)(ws + 0);              // NB*NP f32   = 615936 B
  int*   prior_arg = (int*)(ws + 615936);           // NB*NP i32
  int*   conf      = (int*)(ws + 1231872);          // NB*NP i32
  float* marks     = (float*)(ws + 1847808);        // NB*NP f32
  unsigned char* dm = (unsigned char*)(ws + 2463744); // NB*NOBJ*138*138 u8 = 1218816
  int*   pos_list  = (int*)(ws + 3682560);          // NB*128 i32
  int*   npos_arr  = (int*)(ws + 3686656);          // NB i32
  int*   nneg_arr  = (int*)(ws + 3686688);          // NB i32
  float* scale_arr = (float*)(ws + 3686720);        // NB f32
  float* accum     = (float*)(ws + 3686752);        // 4 f32
  unsigned long long* forced = (unsigned long long*)(ws + 3686784); // NB*NOBJ u64
  (void)in_sizes; (void)n_in; (void)out_size; (void)ws_size;

  const int PB = (NP + 255) / 256;  // 76 prior-blocks

  init_kernel<<<1, 128, 0, stream>>>(accum, forced);
  {
    dim3 g(PB, NB);
    match1_kernel<<<g, 256, 0, stream>>>(priors, box_gt, prior_max, prior_arg, forced);
  }
  match2_kernel<<<1, 64, 0, stream>>>(forced, prior_max, prior_arg);
  {
    dim3 g(PB, NB);
    conf_kernel<<<g, 256, 0, stream>>>(priors, box_gt, class_gt, box_p,
                                       prior_max, prior_arg, conf, accum);
  }
  poslist_kernel<<<NB, 256, 0, stream>>>(conf, pos_list, npos_arr, nneg_arr, scale_arr);
  mark_kernel<<<(NB * NP + 3) / 4, 256, 0, stream>>>(class_p, conf, marks, accum);
  select_kernel<<<NB, 1024, 0, stream>>>(marks, nneg_arr, accum);
  resize_kernel<<<(NB * NOBJ * PHD * PWD + 255) / 256, 256, 0, stream>>>(mask_gt, dm);
  {
    dim3 g((PHD * PWD + 255) / 256, NB);
    maskloss_kernel<<<g, 256, 0, stream>>>(proto_p, coef_p, box_gt, prior_arg, dm,
                                           pos_list, npos_arr, scale_arr, accum);
  }
  finalize_kernel<<<1, 1, 0, stream>>>(accum, (float*)d_out);
}

// Round 3
// 510.746 us; speedup vs baseline: 1.6685x; 1.0466x over previous
//
#include <hip/hip_runtime.h>
#include <math.h>

#define NB 8
#define NP 19248
#define NC 81
#define NOBJ 8
#define NK 32
#define PHD 138
#define PWD 138
#define NPX (PHD * PWD)   // 19044
#define IH 550
#define IW 550

typedef short v8s __attribute__((ext_vector_type(8)));
typedef float v4f __attribute__((ext_vector_type(4)));

__device__ __forceinline__ float wave_sum(float v) {
  #pragma unroll
  for (int o = 32; o >= 1; o >>= 1) v += __shfl_xor(v, o);
  return v;
}
__device__ __forceinline__ int wave_sum_i(int v) {
  #pragma unroll
  for (int o = 32; o >= 1; o >>= 1) v += __shfl_xor(v, o);
  return v;
}
__device__ __forceinline__ unsigned short f2bf(float f) {
  unsigned u = __float_as_uint(f);
  u = (u + 0x7fffu + ((u >> 16) & 1u)) >> 16;
  return (unsigned short)u;
}

// accum layout: [0]=loss_b_raw, [1]=loss_c, [2]=loss_m_raw
__global__ void init_kernel(float* accum, unsigned long long* forced) {
  if (threadIdx.x < 4) accum[threadIdx.x] = 0.f;
  if (threadIdx.x < NB * NOBJ) forced[threadIdx.x] = 0ull;
}

// grid (76, NB): one prior per thread. Per-prior max/arg + per-gt argmax via packed u64 atomicMax.
__global__ __launch_bounds__(256) void match1_kernel(
    const float* __restrict__ priors, const float* __restrict__ box_gt,
    float* __restrict__ prior_max, int* __restrict__ prior_arg,
    unsigned long long* __restrict__ forced)
{
  int b = blockIdx.y, tid = threadIdx.x;
  int p = blockIdx.x * 256 + tid;
  int lane = tid & 63;
  __shared__ float gx1[NOBJ], gy1[NOBJ], gx2[NOBJ], gy2[NOBJ], garea[NOBJ];
  if (tid < NOBJ) {
    const float* g = box_gt + (b * NOBJ + tid) * 4;
    float x1 = g[0], y1 = g[1], x2 = g[2], y2 = g[3];
    gx1[tid] = x1; gy1[tid] = y1; gx2[tid] = x2; gy2[tid] = y2;
    garea[tid] = (x2 - x1) * (y2 - y1);
  }
  __syncthreads();

  bool act = p < NP;
  float dx1 = 0, dy1 = 0, dx2 = 0, dy2 = 0, darea = 1.f;
  if (act) {
    const float* pr = priors + p * 4;
    float cx = pr[0], cy = pr[1], w = pr[2], h = pr[3];
    dx1 = cx - w * 0.5f; dy1 = cy - h * 0.5f;
    dx2 = cx + w * 0.5f; dy2 = cy + h * 0.5f;
    darea = (dx2 - dx1) * (dy2 - dy1);
  }
  float pmax = -1.f; int parg = 0;
  unsigned long long pk[NOBJ];
  #pragma unroll
  for (int j = 0; j < NOBJ; j++) {
    float ix = fmaxf(fminf(gx2[j], dx2) - fmaxf(gx1[j], dx1), 0.f);
    float iy = fmaxf(fminf(gy2[j], dy2) - fmaxf(gy1[j], dy1), 0.f);
    float inter = ix * iy;
    float iou = inter / (garea[j] + darea - inter);
    if (j == 0) { pmax = iou; parg = 0; }
    else if (iou > pmax) { pmax = iou; parg = j; }   // strict > : first-index tie-break
    pk[j] = act ? ((((unsigned long long)__float_as_uint(iou)) << 32)
                   | (unsigned long long)(0x7fffffffu - (unsigned)p))
                : 0ull;
  }
  if (act) {
    prior_max[b * NP + p] = pmax;
    prior_arg[b * NP + p] = parg;
  }
  #pragma unroll
  for (int j = 0; j < NOBJ; j++) {
    unsigned long long v = pk[j];
    #pragma unroll
    for (int o = 32; o >= 1; o >>= 1) {
      unsigned long long ov = __shfl_xor(v, o);
      if (ov > v) v = ov;
    }
    if (lane == 0) atomicMax(&forced[b * NOBJ + j], v);
  }
}

// Apply forced matches sequentially per batch (later j wins on duplicates).
__global__ void match2_kernel(const unsigned long long* __restrict__ forced,
                              float* __restrict__ prior_max, int* __restrict__ prior_arg) {
  int b = threadIdx.x;
  if (b < NB) {
    for (int j = 0; j < NOBJ; j++) {
      unsigned long long v = forced[b * NOBJ + j];
      int i = 0x7fffffff - (int)(v & 0xffffffffull);
      prior_max[b * NP + i] = 2.0f;
      prior_arg[b * NP + i] = j;
    }
  }
}

// grid (76, NB): conf per prior + inline smooth-L1 box loss for positives.
__global__ __launch_bounds__(256) void conf_kernel(
    const float* __restrict__ priors, const float* __restrict__ box_gt,
    const int* __restrict__ class_gt, const float* __restrict__ box_p,
    const float* __restrict__ prior_max, const int* __restrict__ prior_arg,
    int* __restrict__ conf, float* accum)
{
  int b = blockIdx.y, tid = threadIdx.x;
  int p = blockIdx.x * 256 + tid;
  int lane = tid & 63, wid = tid >> 6;
  __shared__ float lbw[4];
  float lb = 0.f;
  if (p < NP) {
    float m = prior_max[b * NP + p];
    int j = prior_arg[b * NP + p];
    int cf = class_gt[b * NOBJ + j] + 1;
    if (m < 0.5f) cf = -1;
    if (m < 0.4f) cf = 0;
    conf[b * NP + p] = cf;
    if (cf > 0) {
      const float* g = box_gt + (b * NOBJ + j) * 4;
      float x1 = g[0], y1 = g[1], x2 = g[2], y2 = g[3];
      const float* pr = priors + p * 4;
      float pcx = pr[0], pcy = pr[1], prw = pr[2], prh = pr[3];
      float o4[4];
      o4[0] = ((x1 + x2) * 0.5f - pcx) / (0.1f * prw);
      o4[1] = ((y1 + y2) * 0.5f - pcy) / (0.1f * prh);
      o4[2] = logf((x2 - x1) / prw) / 0.2f;
      o4[3] = logf((y2 - y1) / prh) / 0.2f;
      const float* bp = box_p + (b * NP + p) * 4;
      #pragma unroll
      for (int c = 0; c < 4; c++) {
        float d = fabsf(bp[c] - o4[c]);
        lb += (d < 1.f) ? 0.5f * d * d : d - 0.5f;
      }
    }
  }
  lb = wave_sum(lb);
  if (lane == 0) lbw[wid] = lb;
  __syncthreads();
  if (tid == 0) atomicAdd(&accum[0], lbw[0] + lbw[1] + lbw[2] + lbw[3]);
}

// One block per batch: segment count -> LDS scan -> ordered scatter of first 128 positives.
__global__ __launch_bounds__(256) void poslist_kernel(
    const int* __restrict__ conf, int* __restrict__ pos_list,
    int* __restrict__ npos_arr, int* __restrict__ nneg_arr, float* __restrict__ scale_arr)
{
  int b = blockIdx.x, tid = threadIdx.x;
  const int SEG = 76;  // 256*76 = 19456 >= NP
  int s0 = tid * SEG, s1 = s0 + SEG; if (s1 > NP) s1 = NP;
  int cnt = 0;
  for (int p = s0; p < s1; p++) cnt += (conf[b * NP + p] > 0) ? 1 : 0;
  __shared__ int sc[256];
  sc[tid] = cnt;
  __syncthreads();
  #pragma unroll
  for (int off = 1; off < 256; off <<= 1) {
    int v = (tid >= off) ? sc[tid - off] : 0;
    __syncthreads();
    sc[tid] += v;
    __syncthreads();
  }
  int base = sc[tid] - cnt;   // exclusive prefix
  if (cnt > 0 && base < 128) {
    int r = base;
    for (int p = s0; p < s1; p++) {
      if (conf[b * NP + p] > 0) {
        if (r < 128) pos_list[b * 128 + r] = p;
        r++;
      }
    }
  }
  if (tid == 255) {
    int np = sc[255];
    npos_arr[b] = np;
    int nn = 3 * np; if (nn > NP - 1) nn = NP - 1;
    nneg_arr[b] = nn;
    scale_arr[b] = (np > 100) ? (float)np / 100.0f : 1.0f;
  }
}

// 16 lanes per row, 4 rows per wave, 16 rows per block. NB*NP = 153984 = 16*9624 exactly.
__global__ __launch_bounds__(256) void mark_kernel(
    const float* __restrict__ class_p, const int* __restrict__ conf,
    float* __restrict__ marks, float* accum)
{
  int lane = threadIdx.x & 63, wv = threadIdx.x >> 6;
  int sub = lane & 15, grp = lane >> 4;
  int row = blockIdx.x * 16 + wv * 4 + grp;
  const float* cp = class_p + (size_t)row * NC;
  float v[6];
  #pragma unroll
  for (int k = 0; k < 6; k++) {
    int c = sub + 16 * k;
    v[k] = (c < NC) ? cp[c] : -INFINITY;
  }
  float m = v[0];
  #pragma unroll
  for (int k = 1; k < 6; k++) m = fmaxf(m, v[k]);
  #pragma unroll
  for (int o = 1; o < 16; o <<= 1) m = fmaxf(m, __shfl_xor(m, o));
  float s = 0.f;
  #pragma unroll
  for (int k = 0; k < 6; k++) s += __expf(v[k] - m);
  #pragma unroll
  for (int o = 1; o < 16; o <<= 1) s += __shfl_xor(s, o);
  float lse = m + __logf(s);
  if (sub == 0) {
    int cf = conf[row];
    marks[row] = (cf != 0) ? 0.f : (lse - v[0]);
    if (cf > 0) atomicAdd(&accum[1], lse - cp[cf]);
  }
}

// Per batch, 1024 threads: marks cached in 19 regs/thread; 31-step binary search on uint bits.
__global__ __launch_bounds__(1024) void select_kernel(
    const float* __restrict__ marks, const int* __restrict__ nneg_arr, float* accum)
{
  int b = blockIdx.x, tid = threadIdx.x;
  int lane = tid & 63, wid = tid >> 6;
  float v[19];
  #pragma unroll
  for (int i = 0; i < 19; i++) {
    int p = i * 1024 + tid;
    v[i] = (p < NP) ? marks[b * NP + p] : 0.f;  // pad 0: midpoints are >0, pads never counted
  }
  int k = nneg_arr[b];
  __shared__ unsigned slo, shi;
  __shared__ int wred[16];
  __shared__ float fred[16];
  if (tid == 0) { slo = 0u; shi = 0x7f800000u; }
  __syncthreads();
  while (true) {
    unsigned lo = slo, hi = shi;
    if (hi - lo <= 1u) break;
    unsigned mid = lo + ((hi - lo) >> 1);
    float fmid = __uint_as_float(mid);
    int cnt = 0;
    #pragma unroll
    for (int i = 0; i < 19; i++) cnt += (v[i] >= fmid) ? 1 : 0;
    cnt = wave_sum_i(cnt);
    if (lane == 0) wred[wid] = cnt;
    __syncthreads();
    if (tid == 0) {
      int tot = 0;
      #pragma unroll
      for (int w = 0; w < 16; w++) tot += wred[w];
      if (tot >= k) slo = mid; else shi = mid;
    }
    __syncthreads();
  }
  float thr = __uint_as_float(slo);
  float s = 0.f;
  #pragma unroll
  for (int i = 0; i < 19; i++) if (v[i] >= thr) s += v[i];
  s = wave_sum(s);
  if (lane == 0) fred[wid] = s;
  __syncthreads();
  if (tid == 0) {
    float t = 0.f;
    #pragma unroll
    for (int w = 0; w < 16; w++) t += fred[w];
    atomicAdd(&accum[1], t);
  }
}

// One thread per (b, pixel): antialiased 550->138 resize for all 8 objects, packed bits out.
__global__ __launch_bounds__(256) void resize_kernel(
    const float* __restrict__ mask_gt, unsigned char* __restrict__ gtb)
{
  int idx = blockIdx.x * 256 + threadIdx.x;
  if (idx >= NB * NPX) return;
  int px = idx % NPX;
  int b = idx / NPX;
  int oy = px / PWD, ox = px % PWD;
  const float ks = (float)IH / (float)PHD;  // 550/138
  float sy = (oy + 0.5f) * ks - 0.5f;
  float sx = (ox + 0.5f) * ks - 0.5f;
  int ylo = (int)ceilf(sy - ks); if (ylo < 0) ylo = 0;
  int yhi = (int)floorf(sy + ks); if (yhi > IH - 1) yhi = IH - 1;
  int xlo = (int)ceilf(sx - ks); if (xlo < 0) xlo = 0;
  int xhi = (int)floorf(sx + ks); if (xhi > IW - 1) xhi = IW - 1;
  int ny = yhi - ylo, nx = xhi - xlo;   // inclusive tap counts - 1 (<=8)
  float wy[9], wx[9];
  float wsy = 0.f, wsx = 0.f;
  #pragma unroll
  for (int j = 0; j < 9; j++) {
    float w = (j <= ny) ? fmaxf(0.f, 1.f - fabsf(sy - (float)(ylo + j)) / ks) : 0.f;
    wy[j] = w; wsy += w;
  }
  #pragma unroll
  for (int j = 0; j < 9; j++) {
    float w = (j <= nx) ? fmaxf(0.f, 1.f - fabsf(sx - (float)(xlo + j)) / ks) : 0.f;
    wx[j] = w; wsx += w;
  }
  float thr = 0.5f * wsy * wsx;   // compare acc > thr  <=>  acc/(wsy*wsx) > 0.5
  unsigned byte = 0;
  for (int n = 0; n < NOBJ; n++) {
    const float* mg = mask_gt + (size_t)(b * NOBJ + n) * (IH * IW);
    float acc = 0.f;
    for (int jy = 0; jy <= ny; jy++) {
      const float* rowp = mg + (size_t)(ylo + jy) * IW + xlo;
      float ax = 0.f;
      #pragma unroll
      for (int jx = 0; jx < 9; jx++) {
        if (jx <= nx) ax += wx[jx] * rowp[jx];
      }
      acc += wy[jy] * ax;
    }
    byte |= (acc > thr) ? (1u << n) : 0u;
  }
  gtb[idx] = (unsigned char)byte;
}

// MFMA mask loss: logits = proto(19044x32) @ coef^T(32x112pad) in bf16 16x16x32 tiles.
// Block = 4 waves x 16-pixel M-tiles = 64 pixels; 7 N-tiles of 16 masks (<=100 valid).
__global__ __launch_bounds__(256) void maskloss_kernel(
    const float* __restrict__ proto_p, const float* __restrict__ coef_p,
    const float* __restrict__ box_gt, const int* __restrict__ pmi,
    const unsigned char* __restrict__ gtb, const int* __restrict__ pos_list,
    const int* __restrict__ npos_arr, const float* __restrict__ scale_arr,
    float* accum)
{
  int b = blockIdx.y, tid = threadIdx.x;
  int wv = tid >> 6, lane = tid & 63;
  __shared__ unsigned short s_coef[112 * NK];  // bf16 bits
  __shared__ float s_x1[112], s_x2[112], s_y1[112], s_y2[112], s_inv[112];
  __shared__ int s_gi[112];
  __shared__ unsigned char s_gtb[64];
  __shared__ float fr[4];
  int np = npos_arr[b];
  int mb = np < 100 ? np : 100;

  for (int i = tid; i < 112 * NK; i += 256) {
    int kk = i >> 5, c = i & 31;
    float v = 0.f;
    if (kk < mb) {
      int p = pos_list[b * 128 + kk];
      v = coef_p[((size_t)(b * NP) + p) * NK + c];
    }
    s_coef[i] = f2bf(v);
  }
  for (int kk = tid; kk < 112; kk += 256) {
    float x1 = 0.f, x2 = 0.f, y1 = 0.f, y2 = 0.f, inv = 0.f; int gi = 0;
    if (kk < mb) {
      int p = pos_list[b * 128 + kk];
      gi = pmi[b * NP + p];
      const float* g = box_gt + (b * NOBJ + gi) * 4;
      float bx1 = g[0], by1 = g[1], bx2 = g[2], by2 = g[3];
      float ax = bx1 * 138.f, bx = bx2 * 138.f;
      x1 = fminf(ax, bx); x2 = fmaxf(ax, bx);
      x1 = fmaxf(x1 - 1.f, 0.f); x2 = fminf(x2 + 1.f, 138.f);
      float ay = by1 * 138.f, by_ = by2 * 138.f;
      y1 = fminf(ay, by_); y2 = fmaxf(ay, by_);
      y1 = fmaxf(y1 - 1.f, 0.f); y2 = fminf(y2 + 1.f, 138.f);
      inv = 1.f / ((bx2 - bx1) * (by2 - by1));
    }
    s_x1[kk] = x1; s_x2[kk] = x2; s_y1[kk] = y1; s_y2[kk] = y2;
    s_inv[kk] = inv; s_gi[kk] = gi;
  }
  int px0 = blockIdx.x * 64;
  if (tid < 64) {
    int p = px0 + tid;
    s_gtb[tid] = (p < NPX) ? gtb[b * NPX + p] : 0;
  }
  __syncthreads();

  // B fragments: B[k = (lane>>4)*8 + j][n = lane&15], contiguous 8 k's per lane.
  v8s bfr[7];
  {
    int n_in = lane & 15, kq = (lane >> 4) * 8;
    #pragma unroll
    for (int t = 0; t < 7; t++)
      bfr[t] = *(const v8s*)&s_coef[(t * 16 + n_in) * NK + kq];
  }
  // A fragment: A[m = lane&15][k = (lane>>4)*8 + j], 8 contiguous floats from global.
  int m_in = lane & 15, kq = (lane >> 4) * 8;
  int pixel_a = px0 + wv * 16 + m_in; if (pixel_a > NPX - 1) pixel_a = NPX - 1;
  const float4* ap = (const float4*)(proto_p + ((size_t)b * NPX + pixel_a) * NK + kq);
  float4 a0 = ap[0], a1 = ap[1];
  v8s afr;
  {
    float f[8] = {a0.x, a0.y, a0.z, a0.w, a1.x, a1.y, a1.z, a1.w};
    #pragma unroll
    for (int j = 0; j < 8; j++) afr[j] = (short)f2bf(f[j]);
  }

  float loss = 0.f;
  #pragma unroll
  for (int t = 0; t < 7; t++) {
    v4f acc = {0.f, 0.f, 0.f, 0.f};
    acc = __builtin_amdgcn_mfma_f32_16x16x32_bf16(afr, bfr[t], acc, 0, 0, 0);
    int n = t * 16 + (lane & 15);
    float x1 = s_x1[n], x2 = s_x2[n], y1 = s_y1[n], y2 = s_y2[n], inv = s_inv[n];
    int gi = s_gi[n];
    bool vn = n < mb;
    #pragma unroll
    for (int r = 0; r < 4; r++) {
      int pl = wv * 16 + (lane >> 4) * 4 + r;   // local pixel [0,64)
      int pixel = px0 + pl;
      if (vn && pixel < NPX) {
        int y = pixel / PWD, x = pixel - y * PWD;
        float fx = (float)x, fy = (float)y;
        bool inb = (fx >= x1) && (fx < x2) && (fy >= y1) && (fy < y2);
        float l = acc[r];
        float p_ = inb ? __builtin_amdgcn_rcpf(1.f + __expf(-l)) : 0.f;
        p_ = fminf(fmaxf(p_, 1e-7f), 0.99999988f);
        float gt = (float)((s_gtb[pl] >> gi) & 1);
        float bce = -(gt * __logf(p_) + (1.f - gt) * log1pf(-p_));
        loss += bce * inv;
      }
    }
  }
  loss = wave_sum(loss);
  if (lane == 0) fr[wv] = loss;
  __syncthreads();
  if (tid == 0) atomicAdd(&accum[2], (fr[0] + fr[1] + fr[2] + fr[3]) * scale_arr[b]);
}

__global__ void finalize_kernel(const float* accum, float* out) {
  out[0] = 1.5f * accum[0] + accum[1] + accum[2] * (6.125f / (138.f * 138.f));
}

extern "C" void kernel_launch(void* const* d_in, const int* in_sizes, int n_in,
                              void* d_out, int out_size, void* d_ws, size_t ws_size,
                              hipStream_t stream) {
  const float* class_p  = (const float*)d_in[0];
  const float* box_p    = (const float*)d_in[1];
  const float* coef_p   = (const float*)d_in[2];
  const float* proto_p  = (const float*)d_in[3];
  const float* priors   = (const float*)d_in[4];
  const float* box_gt   = (const float*)d_in[5];
  const float* mask_gt  = (const float*)d_in[6];
  const int*   class_gt = (const int*)d_in[7];

  char* ws = (char*)d_ws;
  float* prior_max = (float*)(ws + 0);                 // NB*NP f32 = 615936 B
  int*   prior_arg = (int*)(ws + 615936);              // NB*NP i32
  int*   conf      = (int*)(ws + 1231872);             // NB*NP i32
  float* marks     = (float*)(ws + 1847808);           // NB*NP f32
  unsigned char* gtb = (unsigned char*)(ws + 2463744); // NB*NPX u8 = 152352
  int*   pos_list  = (int*)(ws + 2616096);             // NB*128 i32
  int*   npos_arr  = (int*)(ws + 2620192);             // NB i32
  int*   nneg_arr  = (int*)(ws + 2620224);             // NB i32
  float* scale_arr = (float*)(ws + 2620256);           // NB f32
  float* accum     = (float*)(ws + 2620288);           // 4 f32
  unsigned long long* forced = (unsigned long long*)(ws + 2620320); // NB*NOBJ u64
  (void)in_sizes; (void)n_in; (void)out_size; (void)ws_size;

  const int PB = (NP + 255) / 256;  // 76

  init_kernel<<<1, 128, 0, stream>>>(accum, forced);
  {
    dim3 g(PB, NB);
    match1_kernel<<<g, 256, 0, stream>>>(priors, box_gt, prior_max, prior_arg, forced);
  }
  match2_kernel<<<1, 64, 0, stream>>>(forced, prior_max, prior_arg);
  {
    dim3 g(PB, NB);
    conf_kernel<<<g, 256, 0, stream>>>(priors, box_gt, class_gt, box_p,
                                       prior_max, prior_arg, conf, accum);
  }
  poslist_kernel<<<NB, 256, 0, stream>>>(conf, pos_list, npos_arr, nneg_arr, scale_arr);
  mark_kernel<<<(NB * NP) / 16, 256, 0, stream>>>(class_p, conf, marks, accum);
  select_kernel<<<NB, 1024, 0, stream>>>(marks, nneg_arr, accum);
  resize_kernel<<<(NB * NPX + 255) / 256, 256, 0, stream>>>(mask_gt, gtb);
  {
    dim3 g((NPX + 63) / 64, NB);
    maskloss_kernel<<<g, 256, 0, stream>>>(proto_p, coef_p, box_gt, prior_arg, gtb,
                                           pos_list, npos_arr, scale_arr, accum);
  }
  finalize_kernel<<<1, 1, 0, stream>>>(accum, (float*)d_out);
}

// Round 4
// 496.403 us; speedup vs baseline: 1.7167x; 1.0289x over previous
//
#include <hip/hip_runtime.h>
#include <math.h>

#define NB 8
#define NP 19248
#define NC 81
#define NOBJ 8
#define NK 32
#define PHD 138
#define PWD 138
#define NPX (PHD * PWD)   // 19044
#define IH 550
#define IW 550

typedef short v8s __attribute__((ext_vector_type(8)));
typedef float v4f __attribute__((ext_vector_type(4)));

__device__ __forceinline__ float wave_sum(float v) {
  #pragma unroll
  for (int o = 32; o >= 1; o >>= 1) v += __shfl_xor(v, o);
  return v;
}
__device__ __forceinline__ int wave_sum_i(int v) {
  #pragma unroll
  for (int o = 32; o >= 1; o >>= 1) v += __shfl_xor(v, o);
  return v;
}
__device__ __forceinline__ unsigned short f2bf(float f) {
  unsigned u = __float_as_uint(f);
  u = (u + 0x7fffu + ((u >> 16) & 1u)) >> 16;
  return (unsigned short)u;
}

// accum layout: [0]=loss_b_raw, [1]=loss_c, [2]=loss_m_raw
__global__ void init_kernel(float* accum, unsigned long long* forced) {
  if (threadIdx.x < 4) accum[threadIdx.x] = 0.f;
  if (threadIdx.x < NB * NOBJ) forced[threadIdx.x] = 0ull;
}

// grid (76, NB): one prior per thread. Per-prior max/arg + per-gt argmax via packed u64 atomicMax.
__global__ __launch_bounds__(256) void match1_kernel(
    const float* __restrict__ priors, const float* __restrict__ box_gt,
    float* __restrict__ prior_max, int* __restrict__ prior_arg,
    unsigned long long* __restrict__ forced)
{
  int b = blockIdx.y, tid = threadIdx.x;
  int p = blockIdx.x * 256 + tid;
  int lane = tid & 63;
  __shared__ float gx1[NOBJ], gy1[NOBJ], gx2[NOBJ], gy2[NOBJ], garea[NOBJ];
  if (tid < NOBJ) {
    const float* g = box_gt + (b * NOBJ + tid) * 4;
    float x1 = g[0], y1 = g[1], x2 = g[2], y2 = g[3];
    gx1[tid] = x1; gy1[tid] = y1; gx2[tid] = x2; gy2[tid] = y2;
    garea[tid] = (x2 - x1) * (y2 - y1);
  }
  __syncthreads();

  bool act = p < NP;
  float dx1 = 0, dy1 = 0, dx2 = 0, dy2 = 0, darea = 1.f;
  if (act) {
    const float* pr = priors + p * 4;
    float cx = pr[0], cy = pr[1], w = pr[2], h = pr[3];
    dx1 = cx - w * 0.5f; dy1 = cy - h * 0.5f;
    dx2 = cx + w * 0.5f; dy2 = cy + h * 0.5f;
    darea = (dx2 - dx1) * (dy2 - dy1);
  }
  float pmax = -1.f; int parg = 0;
  unsigned long long pk[NOBJ];
  #pragma unroll
  for (int j = 0; j < NOBJ; j++) {
    float ix = fmaxf(fminf(gx2[j], dx2) - fmaxf(gx1[j], dx1), 0.f);
    float iy = fmaxf(fminf(gy2[j], dy2) - fmaxf(gy1[j], dy1), 0.f);
    float inter = ix * iy;
    float iou = inter / (garea[j] + darea - inter);
    if (j == 0) { pmax = iou; parg = 0; }
    else if (iou > pmax) { pmax = iou; parg = j; }   // strict > : first-index tie-break
    pk[j] = act ? ((((unsigned long long)__float_as_uint(iou)) << 32)
                   | (unsigned long long)(0x7fffffffu - (unsigned)p))
                : 0ull;
  }
  if (act) {
    prior_max[b * NP + p] = pmax;
    prior_arg[b * NP + p] = parg;
  }
  #pragma unroll
  for (int j = 0; j < NOBJ; j++) {
    unsigned long long v = pk[j];
    #pragma unroll
    for (int o = 32; o >= 1; o >>= 1) {
      unsigned long long ov = __shfl_xor(v, o);
      if (ov > v) v = ov;
    }
    if (lane == 0) atomicMax(&forced[b * NOBJ + j], v);
  }
}

// Apply forced matches sequentially per batch (later j wins on duplicates).
__global__ void match2_kernel(const unsigned long long* __restrict__ forced,
                              float* __restrict__ prior_max, int* __restrict__ prior_arg) {
  int b = threadIdx.x;
  if (b < NB) {
    for (int j = 0; j < NOBJ; j++) {
      unsigned long long v = forced[b * NOBJ + j];
      int i = 0x7fffffff - (int)(v & 0xffffffffull);
      prior_max[b * NP + i] = 2.0f;
      prior_arg[b * NP + i] = j;
    }
  }
}

// grid (76, NB): conf per prior + inline smooth-L1 box loss for positives.
__global__ __launch_bounds__(256) void conf_kernel(
    const float* __restrict__ priors, const float* __restrict__ box_gt,
    const int* __restrict__ class_gt, const float* __restrict__ box_p,
    const float* __restrict__ prior_max, const int* __restrict__ prior_arg,
    int* __restrict__ conf, float* accum)
{
  int b = blockIdx.y, tid = threadIdx.x;
  int p = blockIdx.x * 256 + tid;
  int lane = tid & 63, wid = tid >> 6;
  __shared__ float lbw[4];
  float lb = 0.f;
  if (p < NP) {
    float m = prior_max[b * NP + p];
    int j = prior_arg[b * NP + p];
    int cf = class_gt[b * NOBJ + j] + 1;
    if (m < 0.5f) cf = -1;
    if (m < 0.4f) cf = 0;
    conf[b * NP + p] = cf;
    if (cf > 0) {
      const float* g = box_gt + (b * NOBJ + j) * 4;
      float x1 = g[0], y1 = g[1], x2 = g[2], y2 = g[3];
      const float* pr = priors + p * 4;
      float pcx = pr[0], pcy = pr[1], prw = pr[2], prh = pr[3];
      float o4[4];
      o4[0] = ((x1 + x2) * 0.5f - pcx) / (0.1f * prw);
      o4[1] = ((y1 + y2) * 0.5f - pcy) / (0.1f * prh);
      o4[2] = logf((x2 - x1) / prw) / 0.2f;
      o4[3] = logf((y2 - y1) / prh) / 0.2f;
      const float* bp = box_p + (b * NP + p) * 4;
      #pragma unroll
      for (int c = 0; c < 4; c++) {
        float d = fabsf(bp[c] - o4[c]);
        lb += (d < 1.f) ? 0.5f * d * d : d - 0.5f;
      }
    }
  }
  lb = wave_sum(lb);
  if (lane == 0) lbw[wid] = lb;
  __syncthreads();
  if (tid == 0) atomicAdd(&accum[0], lbw[0] + lbw[1] + lbw[2] + lbw[3]);
}

// One block per batch: segment count -> LDS scan -> ordered scatter of first 128 positives.
__global__ __launch_bounds__(256) void poslist_kernel(
    const int* __restrict__ conf, int* __restrict__ pos_list,
    int* __restrict__ npos_arr, int* __restrict__ nneg_arr, float* __restrict__ scale_arr)
{
  int b = blockIdx.x, tid = threadIdx.x;
  const int SEG = 76;  // 256*76 = 19456 >= NP
  int s0 = tid * SEG, s1 = s0 + SEG; if (s1 > NP) s1 = NP;
  int cnt = 0;
  for (int p = s0; p < s1; p++) cnt += (conf[b * NP + p] > 0) ? 1 : 0;
  __shared__ int sc[256];
  sc[tid] = cnt;
  __syncthreads();
  #pragma unroll
  for (int off = 1; off < 256; off <<= 1) {
    int v = (tid >= off) ? sc[tid - off] : 0;
    __syncthreads();
    sc[tid] += v;
    __syncthreads();
  }
  int base = sc[tid] - cnt;   // exclusive prefix
  if (cnt > 0 && base < 128) {
    int r = base;
    for (int p = s0; p < s1; p++) {
      if (conf[b * NP + p] > 0) {
        if (r < 128) pos_list[b * 128 + r] = p;
        r++;
      }
    }
  }
  if (tid == 255) {
    int np = sc[255];
    npos_arr[b] = np;
    int nn = 3 * np; if (nn > NP - 1) nn = NP - 1;
    nneg_arr[b] = nn;
    scale_arr[b] = (np > 100) ? (float)np / 100.0f : 1.0f;
  }
}

// 16 lanes per row, 4 rows per wave, 16 rows per block. NB*NP = 153984 = 16*9624 exactly.
__global__ __launch_bounds__(256) void mark_kernel(
    const float* __restrict__ class_p, const int* __restrict__ conf,
    float* __restrict__ marks, float* accum)
{
  int lane = threadIdx.x & 63, wv = threadIdx.x >> 6;
  int sub = lane & 15, grp = lane >> 4;
  int row = blockIdx.x * 16 + wv * 4 + grp;
  const float* cp = class_p + (size_t)row * NC;
  float v[6];
  #pragma unroll
  for (int k = 0; k < 6; k++) {
    int c = sub + 16 * k;
    v[k] = (c < NC) ? cp[c] : -INFINITY;
  }
  float m = v[0];
  #pragma unroll
  for (int k = 1; k < 6; k++) m = fmaxf(m, v[k]);
  #pragma unroll
  for (int o = 1; o < 16; o <<= 1) m = fmaxf(m, __shfl_xor(m, o));
  float s = 0.f;
  #pragma unroll
  for (int k = 0; k < 6; k++) s += __expf(v[k] - m);
  #pragma unroll
  for (int o = 1; o < 16; o <<= 1) s += __shfl_xor(s, o);
  float lse = m + __logf(s);
  if (sub == 0) {
    int cf = conf[row];
    marks[row] = (cf != 0) ? 0.f : (lse - v[0]);
    if (cf > 0) atomicAdd(&accum[1], lse - cp[cf]);
  }
}

// Per batch, 1024 threads: marks cached in 19 regs/thread; 31-step binary search on uint bits.
__global__ __launch_bounds__(1024) void select_kernel(
    const float* __restrict__ marks, const int* __restrict__ nneg_arr, float* accum)
{
  int b = blockIdx.x, tid = threadIdx.x;
  int lane = tid & 63, wid = tid >> 6;
  float v[19];
  #pragma unroll
  for (int i = 0; i < 19; i++) {
    int p = i * 1024 + tid;
    v[i] = (p < NP) ? marks[b * NP + p] : 0.f;  // pad 0: midpoints are >0, pads never counted
  }
  int k = nneg_arr[b];
  __shared__ unsigned slo, shi;
  __shared__ int wred[16];
  __shared__ float fred[16];
  if (tid == 0) { slo = 0u; shi = 0x7f800000u; }
  __syncthreads();
  while (true) {
    unsigned lo = slo, hi = shi;
    if (hi - lo <= 1u) break;
    unsigned mid = lo + ((hi - lo) >> 1);
    float fmid = __uint_as_float(mid);
    int cnt = 0;
    #pragma unroll
    for (int i = 0; i < 19; i++) cnt += (v[i] >= fmid) ? 1 : 0;
    cnt = wave_sum_i(cnt);
    if (lane == 0) wred[wid] = cnt;
    __syncthreads();
    if (tid == 0) {
      int tot = 0;
      #pragma unroll
      for (int w = 0; w < 16; w++) tot += wred[w];
      if (tot >= k) slo = mid; else shi = mid;
    }
    __syncthreads();
  }
  float thr = __uint_as_float(slo);
  float s = 0.f;
  #pragma unroll
  for (int i = 0; i < 19; i++) if (v[i] >= thr) s += v[i];
  s = wave_sum(s);
  if (lane == 0) fred[wid] = s;
  __syncthreads();
  if (tid == 0) {
    float t = 0.f;
    #pragma unroll
    for (int w = 0; w < 16; w++) t += fred[w];
    atomicAdd(&accum[1], t);
  }
}

// One thread per (b,obj,oy,ox): antialiased 550->138 resize, one object per thread.
// 4761 blocks (18.6/CU) vs old 595 — latency-hiding via TLP; byte planes out.
__global__ __launch_bounds__(256) void resize_kernel(
    const float* __restrict__ mask_gt, unsigned char* __restrict__ dmp)
{
  int idx = blockIdx.x * 256 + threadIdx.x;
  if (idx >= NB * NOBJ * NPX) return;
  int ox = idx % PWD;
  int t = idx / PWD;
  int oy = t % PHD;
  int bn = t / PHD;           // b*NOBJ + n
  const float ks = (float)IH / (float)PHD;  // 550/138
  float sy = (oy + 0.5f) * ks - 0.5f;
  float sx = (ox + 0.5f) * ks - 0.5f;
  int ylo = (int)ceilf(sy - ks); if (ylo < 0) ylo = 0;
  int yhi = (int)floorf(sy + ks); if (yhi > IH - 1) yhi = IH - 1;
  int xlo = (int)ceilf(sx - ks); if (xlo < 0) xlo = 0;
  int xhi = (int)floorf(sx + ks); if (xhi > IW - 1) xhi = IW - 1;
  int ny = yhi - ylo, nx = xhi - xlo;   // tap counts - 1 (<=8)
  float wy[9], wx[9];
  float wsy = 0.f, wsx = 0.f;
  #pragma unroll
  for (int j = 0; j < 9; j++) {
    float w = (j <= ny) ? fmaxf(0.f, 1.f - fabsf(sy - (float)(ylo + j)) / ks) : 0.f;
    wy[j] = w; wsy += w;
  }
  #pragma unroll
  for (int j = 0; j < 9; j++) {
    float w = (j <= nx) ? fmaxf(0.f, 1.f - fabsf(sx - (float)(xlo + j)) / ks) : 0.f;
    wx[j] = w; wsx += w;
  }
  float thr = 0.5f * wsy * wsx;   // acc > thr  <=>  acc/(wsy*wsx) > 0.5
  const float* mg = mask_gt + (size_t)bn * (IH * IW);
  float acc = 0.f;
  for (int jy = 0; jy <= ny; jy++) {
    const float* rowp = mg + (size_t)(ylo + jy) * IW + xlo;
    float ax = 0.f;
    #pragma unroll
    for (int jx = 0; jx < 9; jx++) {
      if (jx <= nx) ax += wx[jx] * rowp[jx];
    }
    acc += wy[jy] * ax;
  }
  dmp[idx] = (acc > thr) ? 1 : 0;   // idx == bn*NPX + oy*PWD + ox
}

// MFMA mask loss: logits = proto(19044x32) @ coef^T(32x112pad) in bf16 16x16x32 tiles.
// Block = 4 waves x 16-pixel M-tiles = 64 pixels; 7 N-tiles of 16 masks (<=100 valid).
__global__ __launch_bounds__(256) void maskloss_kernel(
    const float* __restrict__ proto_p, const float* __restrict__ coef_p,
    const float* __restrict__ box_gt, const int* __restrict__ pmi,
    const unsigned char* __restrict__ dmp, const int* __restrict__ pos_list,
    const int* __restrict__ npos_arr, const float* __restrict__ scale_arr,
    float* accum)
{
  int b = blockIdx.y, tid = threadIdx.x;
  int wv = tid >> 6, lane = tid & 63;
  __shared__ unsigned short s_coef[112 * NK];  // bf16 bits
  __shared__ float s_x1[112], s_x2[112], s_y1[112], s_y2[112], s_inv[112];
  __shared__ int s_gi[112];
  __shared__ unsigned char s_gtb[64];
  __shared__ float fr[4];
  int np = npos_arr[b];
  int mb = np < 100 ? np : 100;

  for (int i = tid; i < 112 * NK; i += 256) {
    int kk = i >> 5, c = i & 31;
    float v = 0.f;
    if (kk < mb) {
      int p = pos_list[b * 128 + kk];
      v = coef_p[((size_t)(b * NP) + p) * NK + c];
    }
    s_coef[i] = f2bf(v);
  }
  for (int kk = tid; kk < 112; kk += 256) {
    float x1 = 0.f, x2 = 0.f, y1 = 0.f, y2 = 0.f, inv = 0.f; int gi = 0;
    if (kk < mb) {
      int p = pos_list[b * 128 + kk];
      gi = pmi[b * NP + p];
      const float* g = box_gt + (b * NOBJ + gi) * 4;
      float bx1 = g[0], by1 = g[1], bx2 = g[2], by2 = g[3];
      float ax = bx1 * 138.f, bx = bx2 * 138.f;
      x1 = fminf(ax, bx); x2 = fmaxf(ax, bx);
      x1 = fmaxf(x1 - 1.f, 0.f); x2 = fminf(x2 + 1.f, 138.f);
      float ay = by1 * 138.f, by_ = by2 * 138.f;
      y1 = fminf(ay, by_); y2 = fmaxf(ay, by_);
      y1 = fmaxf(y1 - 1.f, 0.f); y2 = fminf(y2 + 1.f, 138.f);
      inv = 1.f / ((bx2 - bx1) * (by2 - by1));
    }
    s_x1[kk] = x1; s_x2[kk] = x2; s_y1[kk] = y1; s_y2[kk] = y2;
    s_inv[kk] = inv; s_gi[kk] = gi;
  }
  int px0 = blockIdx.x * 64;
  if (tid < 64) {
    int p = px0 + tid;
    unsigned byte = 0;
    if (p < NPX) {
      #pragma unroll
      for (int n = 0; n < NOBJ; n++)
        byte |= ((unsigned)dmp[(size_t)(b * NOBJ + n) * NPX + p]) << n;
    }
    s_gtb[tid] = (unsigned char)byte;
  }
  __syncthreads();

  // B fragments: B[k = (lane>>4)*8 + j][n = lane&15], contiguous 8 k's per lane.
  v8s bfr[7];
  {
    int n_in = lane & 15, kq = (lane >> 4) * 8;
    #pragma unroll
    for (int t = 0; t < 7; t++)
      bfr[t] = *(const v8s*)&s_coef[(t * 16 + n_in) * NK + kq];
  }
  // A fragment: A[m = lane&15][k = (lane>>4)*8 + j], 8 contiguous floats from global.
  int m_in = lane & 15, kq = (lane >> 4) * 8;
  int pixel_a = px0 + wv * 16 + m_in; if (pixel_a > NPX - 1) pixel_a = NPX - 1;
  const float4* ap = (const float4*)(proto_p + ((size_t)b * NPX + pixel_a) * NK + kq);
  float4 a0 = ap[0], a1 = ap[1];
  v8s afr;
  {
    float f[8] = {a0.x, a0.y, a0.z, a0.w, a1.x, a1.y, a1.z, a1.w};
    #pragma unroll
    for (int j = 0; j < 8; j++) afr[j] = (short)f2bf(f[j]);
  }

  float loss = 0.f;
  #pragma unroll
  for (int t = 0; t < 7; t++) {
    v4f acc = {0.f, 0.f, 0.f, 0.f};
    acc = __builtin_amdgcn_mfma_f32_16x16x32_bf16(afr, bfr[t], acc, 0, 0, 0);
    int n = t * 16 + (lane & 15);
    float x1 = s_x1[n], x2 = s_x2[n], y1 = s_y1[n], y2 = s_y2[n], inv = s_inv[n];
    int gi = s_gi[n];
    bool vn = n < mb;
    #pragma unroll
    for (int r = 0; r < 4; r++) {
      int pl = wv * 16 + (lane >> 4) * 4 + r;   // local pixel [0,64)
      int pixel = px0 + pl;
      if (vn && pixel < NPX) {
        int y = pixel / PWD, x = pixel - y * PWD;
        float fx = (float)x, fy = (float)y;
        bool inb = (fx >= x1) && (fx < x2) && (fy >= y1) && (fy < y2);
        float l = acc[r];
        float p_ = inb ? __builtin_amdgcn_rcpf(1.f + __expf(-l)) : 0.f;
        p_ = fminf(fmaxf(p_, 1e-7f), 0.99999988f);
        float gt = (float)((s_gtb[pl] >> gi) & 1);
        float bce = -(gt * __logf(p_) + (1.f - gt) * log1pf(-p_));
        loss += bce * inv;
      }
    }
  }
  loss = wave_sum(loss);
  if (lane == 0) fr[wv] = loss;
  __syncthreads();
  if (tid == 0) atomicAdd(&accum[2], (fr[0] + fr[1] + fr[2] + fr[3]) * scale_arr[b]);
}

__global__ void finalize_kernel(const float* accum, float* out) {
  out[0] = 1.5f * accum[0] + accum[1] + accum[2] * (6.125f / (138.f * 138.f));
}

extern "C" void kernel_launch(void* const* d_in, const int* in_sizes, int n_in,
                              void* d_out, int out_size, void* d_ws, size_t ws_size,
                              hipStream_t stream) {
  const float* class_p  = (const float*)d_in[0];
  const float* box_p    = (const float*)d_in[1];
  const float* coef_p   = (const float*)d_in[2];
  const float* proto_p  = (const float*)d_in[3];
  const float* priors   = (const float*)d_in[4];
  const float* box_gt   = (const float*)d_in[5];
  const float* mask_gt  = (const float*)d_in[6];
  const int*   class_gt = (const int*)d_in[7];

  char* ws = (char*)d_ws;
  float* prior_max = (float*)(ws + 0);                 // NB*NP f32 = 615936 B
  int*   prior_arg = (int*)(ws + 615936);              // NB*NP i32
  int*   conf      = (int*)(ws + 1231872);             // NB*NP i32
  float* marks     = (float*)(ws + 1847808);           // NB*NP f32
  unsigned char* dmp = (unsigned char*)(ws + 2463744); // NB*NOBJ*NPX u8 = 1218816
  int*   pos_list  = (int*)(ws + 3682560);             // NB*128 i32
  int*   npos_arr  = (int*)(ws + 3686656);             // NB i32
  int*   nneg_arr  = (int*)(ws + 3686688);             // NB i32
  float* scale_arr = (float*)(ws + 3686720);           // NB f32
  float* accum     = (float*)(ws + 3686752);           // 4 f32
  unsigned long long* forced = (unsigned long long*)(ws + 3686784); // NB*NOBJ u64
  (void)in_sizes; (void)n_in; (void)out_size; (void)ws_size;

  const int PB = (NP + 255) / 256;  // 76

  init_kernel<<<1, 128, 0, stream>>>(accum, forced);
  {
    dim3 g(PB, NB);
    match1_kernel<<<g, 256, 0, stream>>>(priors, box_gt, prior_max, prior_arg, forced);
  }
  match2_kernel<<<1, 64, 0, stream>>>(forced, prior_max, prior_arg);
  {
    dim3 g(PB, NB);
    conf_kernel<<<g, 256, 0, stream>>>(priors, box_gt, class_gt, box_p,
                                       prior_max, prior_arg, conf, accum);
  }
  poslist_kernel<<<NB, 256, 0, stream>>>(conf, pos_list, npos_arr, nneg_arr, scale_arr);
  mark_kernel<<<(NB * NP) / 16, 256, 0, stream>>>(class_p, conf, marks, accum);
  select_kernel<<<NB, 1024, 0, stream>>>(marks, nneg_arr, accum);
  resize_kernel<<<(NB * NOBJ * NPX + 255) / 256, 256, 0, stream>>>(mask_gt, dmp);
  {
    dim3 g((NPX + 63) / 64, NB);
    maskloss_kernel<<<g, 256, 0, stream>>>(proto_p, coef_p, box_gt, prior_arg, dmp,
                                           pos_list, npos_arr, scale_arr, accum);
  }
  finalize_kernel<<<1, 1, 0, stream>>>(accum, (float*)d_out);
}

// Round 5
// 438.211 us; speedup vs baseline: 1.9446x; 1.1328x over previous
//
#include <hip/hip_runtime.h>
#include <math.h>

#define NB 8
#define NP 19248
#define NC 81
#define NOBJ 8
#define NK 32
#define PHD 138
#define PWD 138
#define NPX (PHD * PWD)   // 19044
#define IH 550
#define IW 550
#define NBLK 76           // ceil(NP/256)

typedef short v8s __attribute__((ext_vector_type(8)));
typedef float v4f __attribute__((ext_vector_type(4)));

__device__ __forceinline__ float wave_sum(float v) {
  #pragma unroll
  for (int o = 32; o >= 1; o >>= 1) v += __shfl_xor(v, o);
  return v;
}
__device__ __forceinline__ int wave_sum_i(int v) {
  #pragma unroll
  for (int o = 32; o >= 1; o >>= 1) v += __shfl_xor(v, o);
  return v;
}
__device__ __forceinline__ unsigned short f2bf(float f) {
  unsigned u = __float_as_uint(f);
  u = (u + 0x7fffu + ((u >> 16) & 1u)) >> 16;
  return (unsigned short)u;
}

// grid (76, NB): one prior per thread. Per-prior max/arg + per-gt argmax via packed u64 atomicMax.
__global__ __launch_bounds__(256) void match1_kernel(
    const float* __restrict__ priors, const float* __restrict__ box_gt,
    float* __restrict__ prior_max, int* __restrict__ prior_arg,
    unsigned long long* __restrict__ forced)
{
  int b = blockIdx.y, tid = threadIdx.x;
  int p = blockIdx.x * 256 + tid;
  int lane = tid & 63;
  __shared__ float gx1[NOBJ], gy1[NOBJ], gx2[NOBJ], gy2[NOBJ], garea[NOBJ];
  if (tid < NOBJ) {
    const float* g = box_gt + (b * NOBJ + tid) * 4;
    float x1 = g[0], y1 = g[1], x2 = g[2], y2 = g[3];
    gx1[tid] = x1; gy1[tid] = y1; gx2[tid] = x2; gy2[tid] = y2;
    garea[tid] = (x2 - x1) * (y2 - y1);
  }
  __syncthreads();

  bool act = p < NP;
  float dx1 = 0, dy1 = 0, dx2 = 0, dy2 = 0, darea = 1.f;
  if (act) {
    const float* pr = priors + p * 4;
    float cx = pr[0], cy = pr[1], w = pr[2], h = pr[3];
    dx1 = cx - w * 0.5f; dy1 = cy - h * 0.5f;
    dx2 = cx + w * 0.5f; dy2 = cy + h * 0.5f;
    darea = (dx2 - dx1) * (dy2 - dy1);
  }
  float pmax = -1.f; int parg = 0;
  unsigned long long pk[NOBJ];
  #pragma unroll
  for (int j = 0; j < NOBJ; j++) {
    float ix = fmaxf(fminf(gx2[j], dx2) - fmaxf(gx1[j], dx1), 0.f);
    float iy = fmaxf(fminf(gy2[j], dy2) - fmaxf(gy1[j], dy1), 0.f);
    float inter = ix * iy;
    float iou = inter / (garea[j] + darea - inter);
    if (j == 0) { pmax = iou; parg = 0; }
    else if (iou > pmax) { pmax = iou; parg = j; }   // strict > : first-index tie-break
    pk[j] = act ? ((((unsigned long long)__float_as_uint(iou)) << 32)
                   | (unsigned long long)(0x7fffffffu - (unsigned)p))
                : 0ull;
  }
  if (act) {
    prior_max[b * NP + p] = pmax;
    prior_arg[b * NP + p] = parg;
  }
  #pragma unroll
  for (int j = 0; j < NOBJ; j++) {
    unsigned long long v = pk[j];
    #pragma unroll
    for (int o = 32; o >= 1; o >>= 1) {
      unsigned long long ov = __shfl_xor(v, o);
      if (ov > v) v = ov;
    }
    if (lane == 0) atomicMax(&forced[b * NOBJ + j], v);
  }
}

// grid (76, NB): forced-match override (later j wins) + conf + smooth-L1 box loss + block pos count.
__global__ __launch_bounds__(256) void conf_kernel(
    const float* __restrict__ priors, const float* __restrict__ box_gt,
    const int* __restrict__ class_gt, const float* __restrict__ box_p,
    const float* __restrict__ prior_max, int* __restrict__ prior_arg,
    const unsigned long long* __restrict__ forced,
    int* __restrict__ conf, int* __restrict__ blkcnt, float* accum)
{
  int b = blockIdx.y, bx = blockIdx.x, tid = threadIdx.x;
  int p = bx * 256 + tid;
  int lane = tid & 63, wid = tid >> 6;
  __shared__ int s_fi[NOBJ];
  __shared__ float lbw[4];
  __shared__ int pcw[4];
  if (tid < NOBJ)
    s_fi[tid] = 0x7fffffff - (int)(forced[b * NOBJ + tid] & 0xffffffffull);
  __syncthreads();
  float lb = 0.f;
  bool flag = false;
  if (p < NP) {
    float m = prior_max[b * NP + p];
    int j = prior_arg[b * NP + p];
    int ov = -1;
    #pragma unroll
    for (int jj = 0; jj < NOBJ; jj++)
      if (p == s_fi[jj]) ov = jj;      // later j wins
    if (ov >= 0) { m = 2.0f; j = ov; prior_arg[b * NP + p] = ov; }
    int cf = class_gt[b * NOBJ + j] + 1;
    if (m < 0.5f) cf = -1;
    if (m < 0.4f) cf = 0;
    conf[b * NP + p] = cf;
    flag = cf > 0;
    if (flag) {
      const float* g = box_gt + (b * NOBJ + j) * 4;
      float x1 = g[0], y1 = g[1], x2 = g[2], y2 = g[3];
      const float* pr = priors + p * 4;
      float pcx = pr[0], pcy = pr[1], prw = pr[2], prh = pr[3];
      float o4[4];
      o4[0] = ((x1 + x2) * 0.5f - pcx) / (0.1f * prw);
      o4[1] = ((y1 + y2) * 0.5f - pcy) / (0.1f * prh);
      o4[2] = logf((x2 - x1) / prw) / 0.2f;
      o4[3] = logf((y2 - y1) / prh) / 0.2f;
      const float* bp = box_p + (b * NP + p) * 4;
      #pragma unroll
      for (int c = 0; c < 4; c++) {
        float d = fabsf(bp[c] - o4[c]);
        lb += (d < 1.f) ? 0.5f * d * d : d - 0.5f;
      }
    }
  }
  unsigned long long bm = __ballot(flag);
  lb = wave_sum(lb);
  if (lane == 0) { lbw[wid] = lb; pcw[wid] = __popcll(bm); }
  __syncthreads();
  if (tid == 0) {
    atomicAdd(&accum[0], lbw[0] + lbw[1] + lbw[2] + lbw[3]);
    blkcnt[b * NBLK + bx] = pcw[0] + pcw[1] + pcw[2] + pcw[3];
  }
}

// grid (76, NB): ordered compaction using blkcnt prefix; last block writes npos/nneg/scale.
__global__ __launch_bounds__(256) void scatter_kernel(
    const int* __restrict__ conf, const int* __restrict__ blkcnt,
    int* __restrict__ pos_list, int* __restrict__ npos_arr,
    int* __restrict__ nneg_arr, float* __restrict__ scale_arr)
{
  int bx = blockIdx.x, b = blockIdx.y, tid = threadIdx.x;
  int lane = tid & 63, wid = tid >> 6;
  __shared__ int s_pre;
  __shared__ int wc[4];
  if (tid < 64) {
    int s = 0;
    if (tid < bx) s += blkcnt[b * NBLK + tid];
    int t2 = tid + 64;
    if (t2 < bx) s += blkcnt[b * NBLK + t2];
    s = wave_sum_i(s);
    if (tid == 0) s_pre = s;
  }
  int p = bx * 256 + tid;
  bool flag = (p < NP) && (conf[b * NP + p] > 0);
  unsigned long long m = __ballot(flag);
  if (lane == 0) wc[wid] = __popcll(m);
  __syncthreads();
  int base = s_pre;
  for (int w = 0; w < wid; w++) base += wc[w];
  int idx = base + __popcll(m & ((1ull << lane) - 1ull));
  if (flag && idx < 128) pos_list[b * 128 + idx] = p;
  if (bx == NBLK - 1 && tid == 0) {
    int np = s_pre + wc[0] + wc[1] + wc[2] + wc[3];
    npos_arr[b] = np;
    int nn = 3 * np; if (nn > NP - 1) nn = NP - 1;
    nneg_arr[b] = nn;
    scale_arr[b] = (np > 100) ? (float)np / 100.0f : 1.0f;
  }
}

// 16 lanes per row, 4 rows per wave, 16 rows per block. NB*NP = 153984 = 16*9624 exactly.
__global__ __launch_bounds__(256) void mark_kernel(
    const float* __restrict__ class_p, const int* __restrict__ conf,
    float* __restrict__ marks, float* accum)
{
  int lane = threadIdx.x & 63, wv = threadIdx.x >> 6;
  int sub = lane & 15, grp = lane >> 4;
  int row = blockIdx.x * 16 + wv * 4 + grp;
  const float* cp = class_p + (size_t)row * NC;
  float v[6];
  #pragma unroll
  for (int k = 0; k < 6; k++) {
    int c = sub + 16 * k;
    v[k] = (c < NC) ? cp[c] : -INFINITY;
  }
  float m = v[0];
  #pragma unroll
  for (int k = 1; k < 6; k++) m = fmaxf(m, v[k]);
  #pragma unroll
  for (int o = 1; o < 16; o <<= 1) m = fmaxf(m, __shfl_xor(m, o));
  float s = 0.f;
  #pragma unroll
  for (int k = 0; k < 6; k++) s += __expf(v[k] - m);
  #pragma unroll
  for (int o = 1; o < 16; o <<= 1) s += __shfl_xor(s, o);
  float lse = m + __logf(s);
  if (sub == 0) {
    int cf = conf[row];
    marks[row] = (cf != 0) ? 0.f : (lse - v[0]);
    if (cf > 0) atomicAdd(&accum[1], lse - cp[cf]);
  }
}

// Per batch, 256 threads x 76 regs: 31-step binary search on uint bits; sum of top-k marks.
__global__ __launch_bounds__(256) void select_kernel(
    const float* __restrict__ marks, const int* __restrict__ nneg_arr, float* accum)
{
  int b = blockIdx.x, tid = threadIdx.x;
  int lane = tid & 63, wid = tid >> 6;
  float v[NBLK];
  #pragma unroll
  for (int i = 0; i < NBLK; i++) {
    int p = i * 256 + tid;
    v[i] = (p < NP) ? marks[b * NP + p] : 0.f;  // pad 0: midpoints > 0, pads never counted
  }
  int k = nneg_arr[b];
  __shared__ unsigned slo, shi;
  __shared__ int wred[4];
  __shared__ float fred[4];
  if (tid == 0) { slo = 0u; shi = 0x7f800000u; }
  __syncthreads();
  while (true) {
    unsigned lo = slo, hi = shi;
    if (hi - lo <= 1u) break;
    unsigned mid = lo + ((hi - lo) >> 1);
    float fmid = __uint_as_float(mid);
    int cnt = 0;
    #pragma unroll
    for (int i = 0; i < NBLK; i++) cnt += (v[i] >= fmid) ? 1 : 0;
    cnt = wave_sum_i(cnt);
    if (lane == 0) wred[wid] = cnt;
    __syncthreads();
    if (tid == 0) {
      int tot = wred[0] + wred[1] + wred[2] + wred[3];
      if (tot >= k) slo = mid; else shi = mid;
    }
    __syncthreads();
  }
  float thr = __uint_as_float(slo);
  float s = 0.f;
  #pragma unroll
  for (int i = 0; i < NBLK; i++) if (v[i] >= thr) s += v[i];
  s = wave_sum(s);
  if (lane == 0) fred[wid] = s;
  __syncthreads();
  if (tid == 0) atomicAdd(&accum[1], fred[0] + fred[1] + fred[2] + fred[3]);
}

// Separable antialiased resize, vertical-first. Block per (oy, bn): coalesced row loads,
// 550-wide tmp in LDS, then 138 horizontal outputs -> byte plane.
__global__ __launch_bounds__(256) void resize_kernel(
    const float* __restrict__ mask_gt, unsigned char* __restrict__ dmp)
{
  int oy = blockIdx.x, bn = blockIdx.y, tid = threadIdx.x;
  __shared__ float tmp[IW];
  const float ks = (float)IH / (float)PHD;  // 550/138 ~ 3.9855
  float sy = (oy + 0.5f) * ks - 0.5f;
  int ylo = (int)ceilf(sy - ks); if (ylo < 0) ylo = 0;
  int yhi = (int)floorf(sy + ks); if (yhi > IH - 1) yhi = IH - 1;
  int ny = yhi - ylo;   // <= 7
  float wy[8];
  float wsy = 0.f;
  #pragma unroll
  for (int j = 0; j < 8; j++) {
    float w = (j <= ny) ? fmaxf(0.f, 1.f - fabsf(sy - (float)(ylo + j)) / ks) : 0.f;
    wy[j] = w; wsy += w;
  }
  const float* mg = mask_gt + (size_t)bn * (IH * IW);
  for (int x = tid; x < IW; x += 256) {
    float a = 0.f;
    #pragma unroll
    for (int j = 0; j < 8; j++) {
      if (j <= ny) a += wy[j] * mg[(size_t)(ylo + j) * IW + x];
    }
    tmp[x] = a;
  }
  __syncthreads();
  if (tid < PWD) {
    int ox = tid;
    float sx = (ox + 0.5f) * ks - 0.5f;
    int xlo = (int)ceilf(sx - ks); if (xlo < 0) xlo = 0;
    int xhi = (int)floorf(sx + ks); if (xhi > IW - 1) xhi = IW - 1;
    int nx = xhi - xlo;   // <= 7
    float wsx = 0.f, vsum = 0.f;
    #pragma unroll
    for (int i = 0; i < 8; i++) {
      float w = (i <= nx) ? fmaxf(0.f, 1.f - fabsf(sx - (float)(xlo + i)) / ks) : 0.f;
      wsx += w;
      vsum += w * tmp[xlo + i];
    }
    dmp[(size_t)bn * NPX + oy * PWD + ox] = (vsum > 0.5f * wsy * wsx) ? 1 : 0;
  }
}

// MFMA mask loss: logits = proto(19044x32) @ coef^T(32x112pad) in bf16 16x16x32 tiles.
__global__ __launch_bounds__(256) void maskloss_kernel(
    const float* __restrict__ proto_p, const float* __restrict__ coef_p,
    const float* __restrict__ box_gt, const int* __restrict__ pmi,
    const unsigned char* __restrict__ dmp, const int* __restrict__ pos_list,
    const int* __restrict__ npos_arr, const float* __restrict__ scale_arr,
    float* accum)
{
  int b = blockIdx.y, tid = threadIdx.x;
  int wv = tid >> 6, lane = tid & 63;
  __shared__ unsigned short s_coef[112 * NK];  // bf16 bits
  __shared__ float s_x1[112], s_x2[112], s_y1[112], s_y2[112], s_inv[112];
  __shared__ int s_gi[112];
  __shared__ unsigned char s_gtb[64];
  __shared__ float fr[4];
  int np = npos_arr[b];
  int mb = np < 100 ? np : 100;

  for (int i = tid; i < 112 * NK; i += 256) {
    int kk = i >> 5, c = i & 31;
    float v = 0.f;
    if (kk < mb) {
      int p = pos_list[b * 128 + kk];
      v = coef_p[((size_t)(b * NP) + p) * NK + c];
    }
    s_coef[i] = f2bf(v);
  }
  for (int kk = tid; kk < 112; kk += 256) {
    float x1 = 0.f, x2 = 0.f, y1 = 0.f, y2 = 0.f, inv = 0.f; int gi = 0;
    if (kk < mb) {
      int p = pos_list[b * 128 + kk];
      gi = pmi[b * NP + p];
      const float* g = box_gt + (b * NOBJ + gi) * 4;
      float bx1 = g[0], by1 = g[1], bx2 = g[2], by2 = g[3];
      float ax = bx1 * 138.f, bx = bx2 * 138.f;
      x1 = fminf(ax, bx); x2 = fmaxf(ax, bx);
      x1 = fmaxf(x1 - 1.f, 0.f); x2 = fminf(x2 + 1.f, 138.f);
      float ay = by1 * 138.f, by_ = by2 * 138.f;
      y1 = fminf(ay, by_); y2 = fmaxf(ay, by_);
      y1 = fmaxf(y1 - 1.f, 0.f); y2 = fminf(y2 + 1.f, 138.f);
      inv = 1.f / ((bx2 - bx1) * (by2 - by1));
    }
    s_x1[kk] = x1; s_x2[kk] = x2; s_y1[kk] = y1; s_y2[kk] = y2;
    s_inv[kk] = inv; s_gi[kk] = gi;
  }
  int px0 = blockIdx.x * 64;
  if (tid < 64) {
    int p = px0 + tid;
    unsigned byte = 0;
    if (p < NPX) {
      #pragma unroll
      for (int n = 0; n < NOBJ; n++)
        byte |= ((unsigned)dmp[(size_t)(b * NOBJ + n) * NPX + p]) << n;
    }
    s_gtb[tid] = (unsigned char)byte;
  }
  __syncthreads();

  v8s bfr[7];
  {
    int n_in = lane & 15, kq = (lane >> 4) * 8;
    #pragma unroll
    for (int t = 0; t < 7; t++)
      bfr[t] = *(const v8s*)&s_coef[(t * 16 + n_in) * NK + kq];
  }
  int m_in = lane & 15, kq = (lane >> 4) * 8;
  int pixel_a = px0 + wv * 16 + m_in; if (pixel_a > NPX - 1) pixel_a = NPX - 1;
  const float4* ap = (const float4*)(proto_p + ((size_t)b * NPX + pixel_a) * NK + kq);
  float4 a0 = ap[0], a1 = ap[1];
  v8s afr;
  {
    float f[8] = {a0.x, a0.y, a0.z, a0.w, a1.x, a1.y, a1.z, a1.w};
    #pragma unroll
    for (int j = 0; j < 8; j++) afr[j] = (short)f2bf(f[j]);
  }

  float loss = 0.f;
  #pragma unroll
  for (int t = 0; t < 7; t++) {
    v4f acc = {0.f, 0.f, 0.f, 0.f};
    acc = __builtin_amdgcn_mfma_f32_16x16x32_bf16(afr, bfr[t], acc, 0, 0, 0);
    int n = t * 16 + (lane & 15);
    float x1 = s_x1[n], x2 = s_x2[n], y1 = s_y1[n], y2 = s_y2[n], inv = s_inv[n];
    int gi = s_gi[n];
    bool vn = n < mb;
    #pragma unroll
    for (int r = 0; r < 4; r++) {
      int pl = wv * 16 + (lane >> 4) * 4 + r;   // local pixel [0,64)
      int pixel = px0 + pl;
      if (vn && pixel < NPX) {
        int y = pixel / PWD, x = pixel - y * PWD;
        float fx = (float)x, fy = (float)y;
        bool inb = (fx >= x1) && (fx < x2) && (fy >= y1) && (fy < y2);
        float l = acc[r];
        float p_ = inb ? __builtin_amdgcn_rcpf(1.f + __expf(-l)) : 0.f;
        p_ = fminf(fmaxf(p_, 1e-7f), 0.99999988f);
        float gt = (float)((s_gtb[pl] >> gi) & 1);
        float bce = -(gt * __logf(p_) + (1.f - gt) * log1pf(-p_));
        loss += bce * inv;
      }
    }
  }
  loss = wave_sum(loss);
  if (lane == 0) fr[wv] = loss;
  __syncthreads();
  if (tid == 0) atomicAdd(&accum[2], (fr[0] + fr[1] + fr[2] + fr[3]) * scale_arr[b]);
}

__global__ void finalize_kernel(const float* accum, float* out) {
  out[0] = 1.5f * accum[0] + accum[1] + accum[2] * (6.125f / (138.f * 138.f));
}

extern "C" void kernel_launch(void* const* d_in, const int* in_sizes, int n_in,
                              void* d_out, int out_size, void* d_ws, size_t ws_size,
                              hipStream_t stream) {
  const float* class_p  = (const float*)d_in[0];
  const float* box_p    = (const float*)d_in[1];
  const float* coef_p   = (const float*)d_in[2];
  const float* proto_p  = (const float*)d_in[3];
  const float* priors   = (const float*)d_in[4];
  const float* box_gt   = (const float*)d_in[5];
  const float* mask_gt  = (const float*)d_in[6];
  const int*   class_gt = (const int*)d_in[7];

  char* ws = (char*)d_ws;
  float* prior_max = (float*)(ws + 0);                 // NB*NP f32 = 615936 B
  int*   prior_arg = (int*)(ws + 615936);              // NB*NP i32
  int*   conf      = (int*)(ws + 1231872);             // NB*NP i32
  float* marks     = (float*)(ws + 1847808);           // NB*NP f32
  unsigned char* dmp = (unsigned char*)(ws + 2463744); // NB*NOBJ*NPX u8 = 1218816
  int*   pos_list  = (int*)(ws + 3682560);             // NB*128 i32 = 4096
  int*   npos_arr  = (int*)(ws + 3686656);             // NB i32
  int*   nneg_arr  = (int*)(ws + 3686688);             // NB i32
  float* scale_arr = (float*)(ws + 3686720);           // NB f32
  float* accum     = (float*)(ws + 3686752);           // 4 f32  (memset region start)
  unsigned long long* forced = (unsigned long long*)(ws + 3686768); // NB*NOBJ u64 = 512
  int*   blkcnt    = (int*)(ws + 3687280);             // NB*NBLK i32 = 2432
  (void)in_sizes; (void)n_in; (void)out_size; (void)ws_size;

  // zero accum (16B) + forced (512B) in one memset node
  hipMemsetAsync((void*)accum, 0, 16 + 512, stream);

  {
    dim3 g(NBLK, NB);
    match1_kernel<<<g, 256, 0, stream>>>(priors, box_gt, prior_max, prior_arg, forced);
    conf_kernel<<<g, 256, 0, stream>>>(priors, box_gt, class_gt, box_p,
                                       prior_max, prior_arg, forced, conf, blkcnt, accum);
    scatter_kernel<<<g, 256, 0, stream>>>(conf, blkcnt, pos_list,
                                          npos_arr, nneg_arr, scale_arr);
  }
  mark_kernel<<<(NB * NP) / 16, 256, 0, stream>>>(class_p, conf, marks, accum);
  select_kernel<<<NB, 256, 0, stream>>>(marks, nneg_arr, accum);
  {
    dim3 g(PHD, NB * NOBJ);
    resize_kernel<<<g, 256, 0, stream>>>(mask_gt, dmp);
  }
  {
    dim3 g((NPX + 63) / 64, NB);
    maskloss_kernel<<<g, 256, 0, stream>>>(proto_p, coef_p, box_gt, prior_arg, dmp,
                                           pos_list, npos_arr, scale_arr, accum);
  }
  finalize_kernel<<<1, 1, 0, stream>>>(accum, (float*)d_out);
}